// Round 10
// baseline (369.119 us; speedup 1.0000x reference)
//
#include <hip/hip_runtime.h>
#include <stdint.h>

// ---------------------------------------------------------------------------
// PTBlock fused implementation (B=8, Cin=64, C=128, N=4096, k=16, HID=512)
// R10 changes (k_knn top at 128us; ~27 of 47 instr/cand was drain overhead
// from the thr=inf early burst + wave-max trigger):
//  - k_knn init-64 phase: first 64 cands via 4x(sort16+merge16r), drain-free,
//    exact r17 via merge discards -> steady accepts ~55->~22, drains ~25->~5
//  - 16 subsets x 256 cands, grid 2048 (8 blocks/CU vs 4; 4-level merge tree)
//  - subset-base + unrolled groups -> all loads use compile-time imm offsets
// ---------------------------------------------------------------------------

typedef __attribute__((ext_vector_type(8))) short s8;
typedef __attribute__((ext_vector_type(4))) float f4;

#define MFMA16(a,b,c) __builtin_amdgcn_mfma_f32_16x16x32_bf16(a,b,c,0,0,0)

__device__ __forceinline__ float bf2f(unsigned short u){
  unsigned x = ((unsigned)u) << 16; return __builtin_bit_cast(float, x);
}
__device__ __forceinline__ unsigned short f2bf(float f){
  unsigned x = __builtin_bit_cast(unsigned, f);
  x = x + 0x7FFFu + ((x >> 16) & 1u);
  return (unsigned short)(x >> 16);
}

// ---------------- u32-key sorting helpers ----------------------------------
__device__ __forceinline__ void ce32(unsigned &a, unsigned &b){
  unsigned mn = min(a, b), mx = max(a, b);
  a = mn; b = mx;
}
__device__ __forceinline__ void sort16_u32(unsigned v[16]){
  #pragma unroll
  for (int p = 1; p < 16; p <<= 1){
    #pragma unroll
    for (int k = p; k >= 1; k >>= 1){
      #pragma unroll
      for (int j = k % p; j + k < 16; j += 2*k){
        #pragma unroll
        for (int i = 0; i < k; ++i){
          if (i + j + k < 16){
            if (((i+j) / (2*p)) == ((i+j+k) / (2*p))) ce32(v[i+j], v[i+j+k]);
          }
        }
      }
    }
  }
}
__device__ __forceinline__ void bitonic16_u32(unsigned v[16]){
  #pragma unroll
  for (int k = 8; k >= 1; k >>= 1){
    #pragma unroll
    for (int i = 0; i < 16; ++i){
      if ((i & k) == 0) ce32(v[i], v[i | k]);
    }
  }
}
// merge two sorted-asc 16-seqs; top<-16 smallest; r17 <- min(r17, 17th of union)
__device__ __forceinline__ void merge16r(unsigned top[16], const unsigned w[16],
                                         unsigned &r17){
  unsigned t[16], m17 = 0xFFFFFFFFu;
  #pragma unroll
  for (int i = 0; i < 16; ++i){
    unsigned a = top[i], b = w[15 - i];
    t[i] = min(a, b);
    m17 = min(m17, max(a, b));
  }
  bitonic16_u32(t);
  #pragma unroll
  for (int i = 0; i < 16; ++i) top[i] = t[i];
  r17 = min(r17, m17);
}
__device__ __forceinline__ void drainP(unsigned* br, int &cnt, unsigned top[16],
                                       unsigned &r17, unsigned &thr){
  unsigned v[16];
  #pragma unroll
  for (int j = 0; j < 16; ++j){
    unsigned t = br[j];
    v[j] = (j < cnt) ? t : 0xFFFFFFFFu;
  }
  cnt = 0;
  sort16_u32(v);
  merge16r(top, v, r17);
  thr = top[15];
}

// ---------------- P1: Wak = Wa@Wk, Waq = Wa@Wq, Wda = Wa@Wd2 ---------------
__global__ __launch_bounds__(128) void k_p1(const float* __restrict__ W_a,
    const float* __restrict__ W_k, const float* __restrict__ W_q, const float* __restrict__ W_d2,
    float* __restrict__ tk, float* __restrict__ tq, float* __restrict__ td){
  int which = blockIdx.x >> 7, row = blockIdx.x & 127, c = threadIdx.x;
  const float* X = (which == 0) ? W_k : ((which == 1) ? W_q : W_d2);
  float* O = (which == 0) ? tk : ((which == 1) ? tq : td);
  float acc = 0.f;
  #pragma unroll 8
  for (int i = 0; i < 128; ++i) acc += W_a[row*128 + i] * X[i*128 + c];
  O[row*128 + c] = acc;
}

// ---------------- P2: pack fragment tables, pp, ball -----------------------
__global__ __launch_bounds__(256) void k_pack(
    const float* __restrict__ p, const float* __restrict__ W_v,
    const float* __restrict__ W_d1, const float* __restrict__ b_d1,
    const float* __restrict__ W_in, const float* __restrict__ W_f1, const float* __restrict__ W_f2,
    const float* __restrict__ W_a, const float* __restrict__ b_a, const float* __restrict__ b_d2,
    const float* __restrict__ W_d2,
    const float* __restrict__ tk, const float* __restrict__ tq, const float* __restrict__ td,
    float4* __restrict__ pp, unsigned short* __restrict__ wcatf, unsigned short* __restrict__ wf1f,
    unsigned short* __restrict__ wf2f, unsigned short* __restrict__ wd2f,
    unsigned short* __restrict__ wdaf, unsigned short* __restrict__ w1f,
    unsigned short* __restrict__ winf, float* __restrict__ ball){
  int id0 = blockIdx.x * blockDim.x + threadIdx.x;
  int stride = gridDim.x * blockDim.x;
  for (int i = id0; i < 32768; i += stride){
    int b = i >> 12, m = i & 4095;
    float xx = p[(b*3 + 0)*4096 + m];
    float yy = p[(b*3 + 1)*4096 + m];
    float zz = p[(b*3 + 2)*4096 + m];
    pp[i] = float4{xx, yy, zz, xx*xx + yy*yy + zz*zz};
  }
  for (int i = id0; i < 49152; i += stride){
    int tg = i >> 11, s = (i >> 9) & 3, l = (i >> 3) & 63, j = i & 7;
    int row = tg*16 + (l & 15), k = s*32 + (l >> 4)*8 + j;
    float v;
    if (row < 128) v = tk[row*128 + k];
    else if (row < 256) v = W_v[(row - 128)*128 + k];
    else v = tq[(row - 256)*128 + k];
    wcatf[i] = f2bf(v);
  }
  for (int i = id0; i < 65536; i += stride){
    int tg = i >> 11, s = (i >> 9) & 3, l = (i >> 3) & 63, j = i & 7;
    int row = tg*16 + (l & 15), k = s*32 + (l >> 4)*8 + j;
    wf1f[i] = f2bf(W_f1[row*128 + k]);
  }
  for (int i = id0; i < 65536; i += stride){
    int mt = i >> 13, s = (i >> 9) & 15, l = (i >> 3) & 63, j = i & 7;
    int row = mt*16 + (l & 15), k = s*32 + (l >> 4)*8 + j;
    wf2f[i] = f2bf(W_f2[row*512 + k]);
  }
  for (int i = id0; i < 16384; i += stride){
    int tg = i >> 11, s = (i >> 9) & 3, l = (i >> 3) & 63, j = i & 7;
    int row = tg*16 + (l & 15), k = s*32 + (l >> 4)*8 + j;
    wd2f[i] = f2bf(W_d2[row*128 + k]);
  }
  for (int i = id0; i < 16384; i += stride){
    int tg = i >> 11, s = (i >> 9) & 3, l = (i >> 3) & 63, j = i & 7;
    int row = tg*16 + (l & 15), k = s*32 + (l >> 4)*8 + j;
    wdaf[i] = f2bf(td[row*128 + k]);
  }
  for (int i = id0; i < 4096; i += stride){
    int tg = i >> 9, l = (i >> 3) & 63, j = i & 7;
    int c = tg*16 + (l & 15);
    float v = 0.f;
    if (l < 16 && j < 4) v = (j < 3) ? W_d1[c*3 + j] : b_d1[c];
    w1f[i] = f2bf(v);
  }
  for (int i = id0; i < 8192; i += stride){
    int tg = i >> 10, s = (i >> 9) & 1, l = (i >> 3) & 63, j = i & 7;
    int row = tg*16 + (l & 15), k = s*32 + (l >> 4)*8 + j;
    winf[i] = f2bf(W_in[row*64 + k]);
  }
  for (int o = id0; o < 128; o += stride){
    float acc = b_a[o];
    for (int c = 0; c < 128; ++c) acc += W_a[o*128 + c] * b_d2[c];
    ball[o] = acc;
  }
}

// ---------------- A: h = W_in x + b_in ; LN1 -> hn --------------------------
__global__ __launch_bounds__(256) void k_a(const float* __restrict__ x,
    const unsigned short* __restrict__ WINF, const float* __restrict__ b_in,
    const float* __restrict__ g1, const float* __restrict__ be1,
    float* __restrict__ H, unsigned short* __restrict__ HN){
  __shared__ unsigned short xT[64][72];
  int tid = threadIdx.x;
  int bb = blockIdx.x >> 6;
  int n0 = (blockIdx.x & 63) * 64;
  for (int i = tid; i < 4096; i += 256){
    int c = i >> 6, nn = i & 63;
    xT[nn][c] = f2bf(x[((size_t)(bb*64 + c))*4096 + n0 + nn]);
  }
  __syncthreads();
  int lane = tid & 63, w = tid >> 6, m16 = lane & 15, g = lane >> 4;
  const char* xb = (const char*)&xT[0][0];
  s8 a0 = *(const s8*)(xb + (w*16 + m16)*144 + 16*g);
  s8 a1 = *(const s8*)(xb + (w*16 + m16)*144 + 64 + 16*g);
  const f4 zf = {0.f, 0.f, 0.f, 0.f};
  f4 acc[8];
  #pragma unroll
  for (int t = 0; t < 8; ++t) acc[t] = zf;
  #pragma unroll
  for (int t = 0; t < 8; ++t){
    s8 b0 = *(const s8*)(WINF + ((size_t)(t*2 + 0)*64 + lane)*8);
    s8 b1 = *(const s8*)(WINF + ((size_t)(t*2 + 1)*64 + lane)*8);
    acc[t] = MFMA16(a0, b0, acc[t]);
    acc[t] = MFMA16(a1, b1, acc[t]);
  }
  float mean[4], rstd[4];
  #pragma unroll
  for (int r = 0; r < 4; ++r){
    float ls = 0.f, lq = 0.f;
    #pragma unroll
    for (int t = 0; t < 8; ++t){
      float v = acc[t][r] + b_in[t*16 + m16];
      ls += v; lq += v*v;
    }
    ls += __shfl_xor(ls, 1); ls += __shfl_xor(ls, 2); ls += __shfl_xor(ls, 4); ls += __shfl_xor(ls, 8);
    lq += __shfl_xor(lq, 1); lq += __shfl_xor(lq, 2); lq += __shfl_xor(lq, 4); lq += __shfl_xor(lq, 8);
    float mn = ls * (1.f/128.f);
    float vr = lq * (1.f/128.f) - mn*mn;
    mean[r] = mn;
    rstd[r] = rsqrtf(vr + 1e-5f);
  }
  int ptbase = blockIdx.x*64 + w*16;
  #pragma unroll
  for (int t = 0; t < 8; ++t){
    int o = t*16 + m16;
    float bi = b_in[o], gg = g1[o], be = be1[o];
    #pragma unroll
    for (int r = 0; r < 4; ++r){
      int pt = ptbase + 4*g + r;
      float v = acc[t][r] + bi;
      H[(size_t)pt*128 + o] = v;
      HN[(size_t)pt*128 + o] = f2bf((v - mean[r])*rstd[r]*gg + be);
    }
  }
}

// ---------------- generic data(A) x table(B) GEMM, K=128 -------------------
template<int MODE>
__global__ __launch_bounds__(256) void k_gemm(const unsigned short* __restrict__ A,
    const unsigned short* __restrict__ Btab, const float* __restrict__ bias,
    unsigned short* __restrict__ out){
  int lane = threadIdx.x & 63, w = threadIdx.x >> 6;
  int m0 = blockIdx.x*64 + w*16;
  int by = blockIdx.y;
  int m16 = lane & 15, g = lane >> 4;
  const f4 zf = {0.f, 0.f, 0.f, 0.f};
  f4 acc[8];
  #pragma unroll
  for (int t = 0; t < 8; ++t) acc[t] = zf;
  #pragma unroll
  for (int s = 0; s < 4; ++s){
    s8 af = *(const s8*)(A + ((size_t)(m0 + m16))*128 + s*32 + g*8);
    #pragma unroll
    for (int t = 0; t < 8; ++t){
      s8 bf = *(const s8*)(Btab + ((size_t)((by*8 + t)*4 + s)*64 + lane)*8);
      acc[t] = MFMA16(af, bf, acc[t]);
    }
  }
  #pragma unroll
  for (int t = 0; t < 8; ++t){
    int col = by*128 + t*16 + m16;
    #pragma unroll
    for (int r = 0; r < 4; ++r){
      int pt = m0 + 4*g + r;
      float v = acc[t][r];
      if (MODE == 0){
        int pos = (col < 128) ? 2*col : ((col < 256) ? 2*(col - 128) + 1 : col);
        out[(size_t)pt*384 + pos] = f2bf(v);
      } else {
        v = fmaxf(v + bias[col], 0.f);
        out[(size_t)pt*512 + col] = f2bf(v);
      }
    }
  }
}

// ---------------- F2: out(B,C,N) += W_f2 @ z^T + b_f2 ----------------------
__global__ __launch_bounds__(256) void k_f2(const unsigned short* __restrict__ wf2f,
    const unsigned short* __restrict__ Z, const float* __restrict__ b_f2,
    float* __restrict__ out){
  int lane = threadIdx.x & 63, w = threadIdx.x >> 6;
  int mt = blockIdx.x*4 + w;
  int p0 = blockIdx.y*128;
  int m16 = lane & 15, g = lane >> 4;
  const f4 zf = {0.f, 0.f, 0.f, 0.f};
  f4 acc[8];
  #pragma unroll
  for (int t = 0; t < 8; ++t) acc[t] = zf;
  #pragma unroll 4
  for (int s = 0; s < 16; ++s){
    s8 af = *(const s8*)(wf2f + ((size_t)(mt*16 + s)*64 + lane)*8);
    #pragma unroll
    for (int t = 0; t < 8; ++t){
      s8 bf = *(const s8*)(Z + (size_t)(p0 + t*16 + m16)*512 + s*32 + g*8);
      acc[t] = MFMA16(af, bf, acc[t]);
    }
  }
  #pragma unroll
  for (int t = 0; t < 8; ++t){
    #pragma unroll
    for (int r = 0; r < 4; ++r){
      int o = mt*16 + 4*g + r;
      int pt = p0 + t*16 + m16;
      int b = pt >> 12, n = pt & 4095;
      size_t ix = (((size_t)(b*128 + o)) << 12) | (unsigned)n;
      out[ix] += acc[t][r] + b_f2[o];
    }
  }
}

// ---------------- KNN: single-scan packed-key exact top-16 -----------------
// grid: 2048 = 8 batches x 256 tiles(16 queries); thread (q=tid&15, sub=tid>>4)
// scans [sub*256, sub*256+256). Init-64: 4x(sort16+merge16r) drain-free.
// Steady: 12x16 with imm-offset loads + buffered drains. 4-level merge tree.
__global__ __launch_bounds__(256, 8) void k_knn(const float4* __restrict__ PP,
    int* __restrict__ IDXo){
  __shared__ __align__(16) char smem[17920];
  int tid = threadIdx.x;
  int b = blockIdx.x >> 8;
  int tile = blockIdx.x & 255;
  int q = tid & 15;
  int sub = tid >> 4;
  int qn = tile*16 + q;
  const float4* pb = PP + (size_t)b*4096;
  float4 me = pb[qn];
  const float4* cb = pb + (sub << 8);

  // ---- init-64: 4 chunks of 16, sorted + merged (exact r17 via discards) ----
  unsigned top32[16];
  unsigned r17 = 0xFFFFFFFFu;
  #pragma unroll
  for (int c = 0; c < 4; ++c){
    unsigned v[16];
    #pragma unroll
    for (int j = 0; j < 16; ++j){
      float4 cd = cb[c*16 + j];
      int m = (sub << 8) + c*16 + j;
      float dx = me.x-cd.x, dy = me.y-cd.y, dz = me.z-cd.z;
      unsigned key = (__builtin_bit_cast(unsigned, dx*dx+dy*dy+dz*dz) & 0xFFFFF000u) | (unsigned)m;
      v[j] = (m == qn) ? 0xFFFFFFFFu : key;
    }
    sort16_u32(v);
    if (c == 0){
      #pragma unroll
      for (int j = 0; j < 16; ++j) top32[j] = v[j];
    } else {
      merge16r(top32, v, r17);
    }
  }
  unsigned thr = top32[15];

  // ---- steady scan: cands 64..255, imm-offset loads, buffered drains ----
  int cnt = 0;
  unsigned* br32 = (unsigned*)(smem + tid*68);
  #pragma unroll 1
  for (int oo = 0; oo < 12; ++oo){
    const float4* ob = cb + 64 + oo*16;
    int mb = (sub << 8) + 64 + oo*16;
    #pragma unroll
    for (int jg = 0; jg < 4; ++jg){
      #pragma unroll
      for (int u = 0; u < 4; ++u){
        int j = jg*4 + u;
        float4 cd = ob[j];
        int m = mb + j;
        float dx = me.x-cd.x, dy = me.y-cd.y, dz = me.z-cd.z;
        unsigned key = (__builtin_bit_cast(unsigned, dx*dx+dy*dy+dz*dz) & 0xFFFFF000u) | (unsigned)m;
        if (m != qn){ if (key < thr){ br32[cnt] = key; ++cnt; } else r17 = min(r17, key); }
      }
      if (__any(cnt >= 13)) drainP(br32, cnt, top32, r17, thr);
    }
  }
  drainP(br32, cnt, top32, r17, thr);

  // ---- merge tree across the 16 subsets: rows of 17 u32 (16 keys + r17) ----
  unsigned* pub = (unsigned*)smem;
  #pragma unroll
  for (int step = 8; step >= 1; step >>= 1){
    __syncthreads();
    if (sub >= step && sub < 2*step){
      unsigned* row = pub + (size_t)((sub - step)*16 + q)*17;
      #pragma unroll
      for (int j = 0; j < 16; ++j) row[j] = top32[j];
      row[16] = r17;
    }
    __syncthreads();
    if (sub < step){
      unsigned other[16];
      unsigned* row = pub + (size_t)(sub*16 + q)*17;
      #pragma unroll
      for (int j = 0; j < 16; ++j) other[j] = row[j];
      r17 = min(r17, row[16]);
      merge16r(top32, other, r17);
    }
  }

  unsigned key16 = top32[15];
  bool flag = false;
  if (sub == 0){
    flag = ((r17 >> 12) - (key16 >> 12)) <= 1u;
    if (!flag){
      int* op = IDXo + ((size_t)(b*4096 + qn))*16;
      #pragma unroll
      for (int j = 0; j < 16; ++j) op[j] = (int)(top32[j] & 0xFFFu);
    }
  }

  // ---- rare exact f64 fixup (wave 0, cooperative per flagged query) ----
  if ((tid >> 6) == 0){
    int lane = tid & 63;
    unsigned long long flags = __ballot(flag);
    int* pcnt = (int*)(smem + 17408);
    unsigned* pool = (unsigned*)(smem + 17412);
    while (flags){
      int L = __ffsll((long long)flags) - 1;
      flags &= flags - 1;
      int qf = tile*16 + L;
      float qx = __shfl(me.x, L), qy = __shfl(me.y, L), qz = __shfl(me.z, L);
      unsigned k16 = __shfl(key16, L);
      unsigned t16 = k16 >> 12;
      unsigned bhi = (t16 >= 0xFFFFDu) ? 0xFFFFFFFFu : ((t16 + 2) << 12);
      if (lane == 0) atomicExch(pcnt, 0);
      #pragma unroll 4
      for (int it = 0; it < 64; ++it){
        int m = it*64 + lane;
        float4 cd = pb[m];
        float dx = qx-cd.x, dy = qy-cd.y, dz = qz-cd.z;
        unsigned bits = __builtin_bit_cast(unsigned, dx*dx+dy*dy+dz*dz);
        if (m != qf && bits < bhi){
          int s = atomicAdd(pcnt, 1);
          if (s < 64) pool[s] = (unsigned)m;
        }
      }
      int pn = atomicAdd(pcnt, 0);
      if (pn > 64) pn = 64;
      unsigned long long kk = ~0ull;
      if (lane < pn){
        int m = pool[lane];
        float4 cd = pb[m];
        double ddx = (double)qx - (double)cd.x;
        double ddy = (double)qy - (double)cd.y;
        double ddz = (double)qz - (double)cd.z;
        double d2 = ddx*ddx + ddy*ddy + ddz*ddz;
        kk = (__builtin_bit_cast(unsigned long long, d2) & ~0xFFFull) | (unsigned)m;
      }
      #pragma unroll
      for (int k2 = 2; k2 <= 64; k2 <<= 1){
        #pragma unroll
        for (int j = k2 >> 1; j >= 1; j >>= 1){
          unsigned long long o = __shfl_xor(kk, j);
          bool up = ((lane & k2) == 0);
          bool keepmin = (((lane & j) == 0) == up);
          unsigned long long mn = kk < o ? kk : o;
          unsigned long long mx = kk < o ? o : kk;
          kk = keepmin ? mn : mx;
        }
      }
      if (lane < 16)
        IDXo[((size_t)(b*4096 + qf))*16 + lane] = (int)(unsigned)(kk & 0xFFFull);
    }
  }
}

// ---------------- ATTN: per-point fused kNN attention ----------------------
// 2 points/wave. LDS per wave: 4608B kv region [2 q][16 m][72 u16] (144B
// rows); t1 scratch (4KB) aliases it during setup. No softmax max-subtract.
__global__ __launch_bounds__(256) void k_attn(const float* __restrict__ pcoord,
    const int* __restrict__ IDX, const unsigned short* __restrict__ QKV,
    const unsigned short* __restrict__ W1F, const unsigned short* __restrict__ WD2F,
    const unsigned short* __restrict__ WDAF, const float* __restrict__ b_d2,
    const float* __restrict__ BALL, unsigned short* __restrict__ Y){
  __shared__ __align__(16) char smem[18432];
  __shared__ int idx_sh[4][2][16];
  int tid = threadIdx.x;
  int w = tid >> 6, lane = tid & 63;
  int m16 = lane & 15, g = lane >> 4;
  int P0 = blockIdx.x*8 + w*2;
  char* wbase = smem + w*4608;
  const f4 zf = {0.f, 0.f, 0.f, 0.f};
  if (lane < 16){
    #pragma unroll
    for (int q = 0; q < 2; ++q) idx_sh[w][q][lane] = IDX[(size_t)(P0 + q)*16 + lane];
  }
  // ---- setup: a[q][s] = A-frags of relu(rel_aug @ W1aug^T), t1 in alias ----
  unsigned short* t1s = (unsigned short*)wbase;
  s8 a[2][4];
  #pragma unroll
  for (int q = 0; q < 2; ++q){
    int pt = P0 + q;
    int bq = pt >> 12, nn = pt & 4095;
    const float* pb = pcoord + (size_t)bq*3*4096;
    s8 arel = {0,0,0,0,0,0,0,0};
    if (lane < 16){
      int jn = idx_sh[w][q][m16];
      float rx = pb[nn] - pb[jn];
      float ry = pb[4096 + nn] - pb[4096 + jn];
      float rz = pb[8192 + nn] - pb[8192 + jn];
      arel[0] = (short)f2bf(rx); arel[1] = (short)f2bf(ry);
      arel[2] = (short)f2bf(rz); arel[3] = (short)0x3F80;
    }
    f4 t1a[8];
    #pragma unroll
    for (int t = 0; t < 8; ++t){
      s8 bw = *(const s8*)(W1F + ((size_t)t*64 + lane)*8);
      t1a[t] = MFMA16(arel, bw, zf);
    }
    #pragma unroll
    for (int t = 0; t < 8; ++t){
      int c = t*16 + m16;
      #pragma unroll
      for (int r = 0; r < 4; ++r){
        int m = 4*g + r;
        int byt = (m*256 + c*2) ^ ((m & 7) << 4);
        t1s[byt >> 1] = f2bf(fmaxf(t1a[t][r], 0.f));
      }
    }
    const char* t1b = (const char*)t1s;
    #pragma unroll
    for (int s = 0; s < 4; ++s){
      int byt = (m16*256 + 64*s + 16*g) ^ ((m16 & 7) << 4);
      a[q][s] = *(const s8*)(t1b + byt);
    }
  }
  // ---- main: 4 passes over o-quarters ----
  #pragma unroll 1
  for (int pass = 0; pass < 4; ++pass){
    // WAR fence: previous pass's kv reads (or t1 reads) drain before overwrite
    asm volatile("s_waitcnt lgkmcnt(0)" ::: "memory");
    __builtin_amdgcn_sched_barrier(0);
    // gather this pass's kv columns + qa row
    uint4 gk[2][2];
    float qv[2];
    #pragma unroll
    for (int q = 0; q < 2; ++q){
      int pt = P0 + q, bq = pt >> 12;
      #pragma unroll
      for (int i2 = 0; i2 < 2; ++i2){
        int mm = i2*8 + (lane >> 3);
        int jn = idx_sh[w][q][mm];
        gk[q][i2] = *(const uint4*)((const char*)QKV
            + ((size_t)(bq*4096 + jn))*768 + pass*128 + (lane & 7)*16);
      }
      qv[q] = bf2f(QKV[(size_t)pt*384 + 256 + pass*32 + (lane & 31)]);
    }
    #pragma unroll
    for (int q = 0; q < 2; ++q){
      #pragma unroll
      for (int i2 = 0; i2 < 2; ++i2)
        *(uint4*)(wbase + q*2304 + (i2*8 + (lane >> 3))*144 + (lane & 7)*16) = gk[q][i2];
    }
    #pragma unroll
    for (int tl = 0; tl < 2; ++tl){
      int tg = pass*2 + tl;
      f4 dacc[2], lacc[2];
      #pragma unroll
      for (int q = 0; q < 2; ++q){ dacc[q] = zf; lacc[q] = zf; }
      #pragma unroll
      for (int s = 0; s < 4; ++s){
        s8 wd2 = *(const s8*)(WD2F + ((size_t)(tg*4 + s)*64 + lane)*8);
        s8 wda = *(const s8*)(WDAF + ((size_t)(tg*4 + s)*64 + lane)*8);
        #pragma unroll
        for (int q = 0; q < 2; ++q){
          dacc[q] = MFMA16(a[q][s], wd2, dacc[q]);
          lacc[q] = MFMA16(a[q][s], wda, lacc[q]);
        }
      }
      int col = tg*16 + m16;
      float bd2c = b_d2[col];
      float ballc = BALL[col];
      #pragma unroll
      for (int q = 0; q < 2; ++q){
        int pt = P0 + q;
        float qbase = __shfl(qv[q], tl*16 + m16) + ballc;
        float lg[4], dd[4], vv[4];
        #pragma unroll
        for (int r = 0; r < 4; ++r){
          int m = 4*g + r;
          unsigned kvp = *(const unsigned*)(wbase + q*2304 + m*144 + (tl*16 + m16)*4);
          float ka = bf2f((unsigned short)(kvp & 0xFFFFu));
          vv[r] = bf2f((unsigned short)(kvp >> 16));
          lg[r] = lacc[q][r] + qbase - ka;
          dd[r] = dacc[q][r] + bd2c;
        }
        // no max-subtraction: logits are O(10), overflow at 88
        float e0 = __expf(lg[0]), e1 = __expf(lg[1]);
        float e2 = __expf(lg[2]), e3 = __expf(lg[3]);
        float ss = e0 + e1 + e2 + e3;
        ss += __shfl_xor(ss, 16); ss += __shfl_xor(ss, 32);
        float inv = 1.f / ss;
        float yp = e0*(vv[0] + dd[0]) + e1*(vv[1] + dd[1])
                 + e2*(vv[2] + dd[2]) + e3*(vv[3] + dd[3]);
        yp *= inv;
        yp += __shfl_xor(yp, 16); yp += __shfl_xor(yp, 32);
        if (lane < 16) Y[(size_t)pt*128 + col] = f2bf(yp);
      }
    }
  }
}

// ---------------- D1: h2 = h + y ; d_out = h2 ; hn2 = LN2(h2) ---------------
__global__ __launch_bounds__(256) void k_d1(const float* __restrict__ H,
    const unsigned short* __restrict__ Y, const float* __restrict__ g2,
    const float* __restrict__ be2, float* __restrict__ outp,
    unsigned short* __restrict__ HN2){
  __shared__ float tile[128*65];
  int tid = threadIdx.x;
  int w = tid >> 6, lane = tid & 63;
  int pt16 = lane & 15, g = lane >> 4;
  int n64 = w*16 + pt16;
  int ptbase = blockIdx.x * 64;
  int pt = ptbase + n64;
  int c0 = g*32;
  const float4* h4 = (const float4*)(H + (size_t)pt*128 + c0);
  const uint4*  y4 = (const uint4*)((const char*)Y + (size_t)pt*256 + (size_t)c0*2);
  float h2[32];
  float ls = 0.f, lq = 0.f;
  #pragma unroll
  for (int i = 0; i < 4; ++i){
    float4 ha = h4[2*i], hb = h4[2*i + 1];
    uint4 yv = y4[i];
    float v0 = ha.x + bf2f((unsigned short)(yv.x & 0xFFFFu));
    float v1 = ha.y + bf2f((unsigned short)(yv.x >> 16));
    float v2 = ha.z + bf2f((unsigned short)(yv.y & 0xFFFFu));
    float v3 = ha.w + bf2f((unsigned short)(yv.y >> 16));
    float v4 = hb.x + bf2f((unsigned short)(yv.z & 0xFFFFu));
    float v5 = hb.y + bf2f((unsigned short)(yv.z >> 16));
    float v6 = hb.z + bf2f((unsigned short)(yv.w & 0xFFFFu));
    float v7 = hb.w + bf2f((unsigned short)(yv.w >> 16));
    h2[8*i+0]=v0; h2[8*i+1]=v1; h2[8*i+2]=v2; h2[8*i+3]=v3;
    h2[8*i+4]=v4; h2[8*i+5]=v5; h2[8*i+6]=v6; h2[8*i+7]=v7;
    ls += v0+v1+v2+v3+v4+v5+v6+v7;
    lq += v0*v0+v1*v1+v2*v2+v3*v3+v4*v4+v5*v5+v6*v6+v7*v7;
  }
  ls += __shfl_xor(ls, 16); ls += __shfl_xor(ls, 32);
  lq += __shfl_xor(lq, 16); lq += __shfl_xor(lq, 32);
  float mn = ls * (1.f/128.f);
  float vr = lq * (1.f/128.f) - mn*mn;
  float rs = rsqrtf(vr + 1e-5f);
  const float4* g4  = (const float4*)(g2 + c0);
  const float4* be4 = (const float4*)(be2 + c0);
  #pragma unroll
  for (int i = 0; i < 4; ++i){
    float4 ga = g4[2*i], gb = g4[2*i+1], ba = be4[2*i], bb2 = be4[2*i+1];
    unsigned uu[4];
    uu[0] = (unsigned)f2bf((h2[8*i+0]-mn)*rs*ga.x + ba.x)
          | ((unsigned)f2bf((h2[8*i+1]-mn)*rs*ga.y + ba.y) << 16);
    uu[1] = (unsigned)f2bf((h2[8*i+2]-mn)*rs*ga.z + ba.z)
          | ((unsigned)f2bf((h2[8*i+3]-mn)*rs*ga.w + ba.w) << 16);
    uu[2] = (unsigned)f2bf((h2[8*i+4]-mn)*rs*gb.x + bb2.x)
          | ((unsigned)f2bf((h2[8*i+5]-mn)*rs*gb.y + bb2.y) << 16);
    uu[3] = (unsigned)f2bf((h2[8*i+6]-mn)*rs*gb.z + bb2.z)
          | ((unsigned)f2bf((h2[8*i+7]-mn)*rs*gb.w + bb2.w) << 16);
    *(uint4*)((char*)HN2 + (size_t)pt*256 + (size_t)c0*2 + i*16)
        = make_uint4(uu[0], uu[1], uu[2], uu[3]);
  }
  int swz = g << 4;
  #pragma unroll
  for (int k = 0; k < 32; ++k)
    tile[(c0 + k)*65 + (n64 ^ swz)] = h2[k];
  __syncthreads();
  int bb = ptbase >> 12;
  int nb = ptbase & 4095;
  #pragma unroll 8
  for (int k = 0; k < 32; ++k){
    int c = w*32 + k;
    float v = tile[c*65 + (lane ^ ((((unsigned)c >> 5) & 3) << 4))];
    outp[(((size_t)(bb*128 + c)) << 12) | (unsigned)(nb + lane)] = v;
  }
}

// ---------------------------------------------------------------------------
extern "C" void kernel_launch(void* const* d_in, const int* in_sizes, int n_in,
                              void* d_out, int out_size, void* d_ws, size_t ws_size,
                              hipStream_t stream){
  const float* x    = (const float*)d_in[0];
  const float* p    = (const float*)d_in[1];
  const float* W_in = (const float*)d_in[2];
  const float* b_in = (const float*)d_in[3];
  const float* W_q  = (const float*)d_in[4];
  const float* W_k  = (const float*)d_in[5];
  const float* W_v  = (const float*)d_in[6];
  const float* W_d1 = (const float*)d_in[7];
  const float* b_d1 = (const float*)d_in[8];
  const float* W_d2 = (const float*)d_in[9];
  const float* b_d2 = (const float*)d_in[10];
  const float* W_a  = (const float*)d_in[11];
  const float* b_a  = (const float*)d_in[12];
  const float* g1   = (const float*)d_in[13];
  const float* be1  = (const float*)d_in[14];
  const float* g2   = (const float*)d_in[15];
  const float* be2  = (const float*)d_in[16];
  const float* W_f1 = (const float*)d_in[17];
  const float* b_f1 = (const float*)d_in[18];
  const float* W_f2 = (const float*)d_in[19];
  const float* b_f2 = (const float*)d_in[20];
  float* out = (float*)d_out;
  char* ws = (char*)d_ws;

  float*          H    = (float*)(ws + 0);
  unsigned short* HN   = (unsigned short*)(ws + 16777216);
  unsigned short* QKV  = (unsigned short*)(ws + 25165824);
  unsigned short* Z    = (unsigned short*)(ws + 16777216);  // alias HN+QKV
  unsigned short* Y    = (unsigned short*)(ws + 50331648);
  unsigned short* HN2  = (unsigned short*)(ws + 58720256);
  int*            IDX  = (int*)(ws + 67108864);
  float4*         PP   = (float4*)(ws + 69206016);
  char* tab = ws + 69730304;
  unsigned short* WCATF = (unsigned short*)(tab + 0);
  unsigned short* WF1F  = (unsigned short*)(tab + 98304);
  unsigned short* WF2F  = (unsigned short*)(tab + 229376);
  unsigned short* WD2F  = (unsigned short*)(tab + 360448);
  unsigned short* WDAF  = (unsigned short*)(tab + 393216);
  unsigned short* W1F   = (unsigned short*)(tab + 425984);
  unsigned short* WINF  = (unsigned short*)(tab + 434176);
  float*          BALL  = (float*)(tab + 450560);
  float*          TK    = (float*)(tab + 451072);
  float*          TQ    = (float*)(tab + 516608);
  float*          TD    = (float*)(tab + 582144);

  k_p1<<<dim3(384), dim3(128), 0, stream>>>(W_a, W_k, W_q, W_d2, TK, TQ, TD);
  k_pack<<<dim3(256), dim3(256), 0, stream>>>(p, W_v, W_d1, b_d1, W_in, W_f1, W_f2,
      W_a, b_a, b_d2, W_d2, TK, TQ, TD,
      PP, WCATF, WF1F, WF2F, WD2F, WDAF, W1F, WINF, BALL);
  k_knn<<<dim3(2048), dim3(256), 0, stream>>>(PP, IDX);
  k_a<<<dim3(512), dim3(256), 0, stream>>>(x, WINF, b_in, g1, be1, H, HN);
  k_gemm<0><<<dim3(512, 3), dim3(256), 0, stream>>>(HN, WCATF, nullptr, QKV);
  k_attn<<<dim3(4096), dim3(256), 0, stream>>>(p, IDX, QKV, W1F, WD2F, WDAF, b_d2, BALL, Y);
  k_d1<<<dim3(512), dim3(256), 0, stream>>>(H, Y, g2, be2, out, HN2);
  k_gemm<1><<<dim3(512, 4), dim3(256), 0, stream>>>(HN2, WF1F, b_f1, Z);
  k_f2<<<dim3(2, 256), dim3(256), 0, stream>>>(WF2F, Z, b_f2, out);
}

// Round 11
// 351.965 us; speedup vs baseline: 1.0487x; 1.0487x over previous
//
#include <hip/hip_runtime.h>
#include <stdint.h>

// ---------------------------------------------------------------------------
// PTBlock fused implementation (B=8, Cin=64, C=128, N=4096, k=16, HID=512)
// R11 change (R10 spilled AGAIN: launch_bounds(256,8) + init-64's ~90 VGPR
// pressure -> 196MB scratch WRITE): drop the forced bound -> plain (256).
// Algorithm unchanged from R10 (init-64 drain-free, 16 subsets x 256,
// imm-offset loads, 4-level merge tree).
// ---------------------------------------------------------------------------

typedef __attribute__((ext_vector_type(8))) short s8;
typedef __attribute__((ext_vector_type(4))) float f4;

#define MFMA16(a,b,c) __builtin_amdgcn_mfma_f32_16x16x32_bf16(a,b,c,0,0,0)

__device__ __forceinline__ float bf2f(unsigned short u){
  unsigned x = ((unsigned)u) << 16; return __builtin_bit_cast(float, x);
}
__device__ __forceinline__ unsigned short f2bf(float f){
  unsigned x = __builtin_bit_cast(unsigned, f);
  x = x + 0x7FFFu + ((x >> 16) & 1u);
  return (unsigned short)(x >> 16);
}

// ---------------- u32-key sorting helpers ----------------------------------
__device__ __forceinline__ void ce32(unsigned &a, unsigned &b){
  unsigned mn = min(a, b), mx = max(a, b);
  a = mn; b = mx;
}
__device__ __forceinline__ void sort16_u32(unsigned v[16]){
  #pragma unroll
  for (int p = 1; p < 16; p <<= 1){
    #pragma unroll
    for (int k = p; k >= 1; k >>= 1){
      #pragma unroll
      for (int j = k % p; j + k < 16; j += 2*k){
        #pragma unroll
        for (int i = 0; i < k; ++i){
          if (i + j + k < 16){
            if (((i+j) / (2*p)) == ((i+j+k) / (2*p))) ce32(v[i+j], v[i+j+k]);
          }
        }
      }
    }
  }
}
__device__ __forceinline__ void bitonic16_u32(unsigned v[16]){
  #pragma unroll
  for (int k = 8; k >= 1; k >>= 1){
    #pragma unroll
    for (int i = 0; i < 16; ++i){
      if ((i & k) == 0) ce32(v[i], v[i | k]);
    }
  }
}
// merge two sorted-asc 16-seqs; top<-16 smallest; r17 <- min(r17, 17th of union)
__device__ __forceinline__ void merge16r(unsigned top[16], const unsigned w[16],
                                         unsigned &r17){
  unsigned t[16], m17 = 0xFFFFFFFFu;
  #pragma unroll
  for (int i = 0; i < 16; ++i){
    unsigned a = top[i], b = w[15 - i];
    t[i] = min(a, b);
    m17 = min(m17, max(a, b));
  }
  bitonic16_u32(t);
  #pragma unroll
  for (int i = 0; i < 16; ++i) top[i] = t[i];
  r17 = min(r17, m17);
}
__device__ __forceinline__ void drainP(unsigned* br, int &cnt, unsigned top[16],
                                       unsigned &r17, unsigned &thr){
  unsigned v[16];
  #pragma unroll
  for (int j = 0; j < 16; ++j){
    unsigned t = br[j];
    v[j] = (j < cnt) ? t : 0xFFFFFFFFu;
  }
  cnt = 0;
  sort16_u32(v);
  merge16r(top, v, r17);
  thr = top[15];
}

// ---------------- P1: Wak = Wa@Wk, Waq = Wa@Wq, Wda = Wa@Wd2 ---------------
__global__ __launch_bounds__(128) void k_p1(const float* __restrict__ W_a,
    const float* __restrict__ W_k, const float* __restrict__ W_q, const float* __restrict__ W_d2,
    float* __restrict__ tk, float* __restrict__ tq, float* __restrict__ td){
  int which = blockIdx.x >> 7, row = blockIdx.x & 127, c = threadIdx.x;
  const float* X = (which == 0) ? W_k : ((which == 1) ? W_q : W_d2);
  float* O = (which == 0) ? tk : ((which == 1) ? tq : td);
  float acc = 0.f;
  #pragma unroll 8
  for (int i = 0; i < 128; ++i) acc += W_a[row*128 + i] * X[i*128 + c];
  O[row*128 + c] = acc;
}

// ---------------- P2: pack fragment tables, pp, ball -----------------------
__global__ __launch_bounds__(256) void k_pack(
    const float* __restrict__ p, const float* __restrict__ W_v,
    const float* __restrict__ W_d1, const float* __restrict__ b_d1,
    const float* __restrict__ W_in, const float* __restrict__ W_f1, const float* __restrict__ W_f2,
    const float* __restrict__ W_a, const float* __restrict__ b_a, const float* __restrict__ b_d2,
    const float* __restrict__ W_d2,
    const float* __restrict__ tk, const float* __restrict__ tq, const float* __restrict__ td,
    float4* __restrict__ pp, unsigned short* __restrict__ wcatf, unsigned short* __restrict__ wf1f,
    unsigned short* __restrict__ wf2f, unsigned short* __restrict__ wd2f,
    unsigned short* __restrict__ wdaf, unsigned short* __restrict__ w1f,
    unsigned short* __restrict__ winf, float* __restrict__ ball){
  int id0 = blockIdx.x * blockDim.x + threadIdx.x;
  int stride = gridDim.x * blockDim.x;
  for (int i = id0; i < 32768; i += stride){
    int b = i >> 12, m = i & 4095;
    float xx = p[(b*3 + 0)*4096 + m];
    float yy = p[(b*3 + 1)*4096 + m];
    float zz = p[(b*3 + 2)*4096 + m];
    pp[i] = float4{xx, yy, zz, xx*xx + yy*yy + zz*zz};
  }
  for (int i = id0; i < 49152; i += stride){
    int tg = i >> 11, s = (i >> 9) & 3, l = (i >> 3) & 63, j = i & 7;
    int row = tg*16 + (l & 15), k = s*32 + (l >> 4)*8 + j;
    float v;
    if (row < 128) v = tk[row*128 + k];
    else if (row < 256) v = W_v[(row - 128)*128 + k];
    else v = tq[(row - 256)*128 + k];
    wcatf[i] = f2bf(v);
  }
  for (int i = id0; i < 65536; i += stride){
    int tg = i >> 11, s = (i >> 9) & 3, l = (i >> 3) & 63, j = i & 7;
    int row = tg*16 + (l & 15), k = s*32 + (l >> 4)*8 + j;
    wf1f[i] = f2bf(W_f1[row*128 + k]);
  }
  for (int i = id0; i < 65536; i += stride){
    int mt = i >> 13, s = (i >> 9) & 15, l = (i >> 3) & 63, j = i & 7;
    int row = mt*16 + (l & 15), k = s*32 + (l >> 4)*8 + j;
    wf2f[i] = f2bf(W_f2[row*512 + k]);
  }
  for (int i = id0; i < 16384; i += stride){
    int tg = i >> 11, s = (i >> 9) & 3, l = (i >> 3) & 63, j = i & 7;
    int row = tg*16 + (l & 15), k = s*32 + (l >> 4)*8 + j;
    wd2f[i] = f2bf(W_d2[row*128 + k]);
  }
  for (int i = id0; i < 16384; i += stride){
    int tg = i >> 11, s = (i >> 9) & 3, l = (i >> 3) & 63, j = i & 7;
    int row = tg*16 + (l & 15), k = s*32 + (l >> 4)*8 + j;
    wdaf[i] = f2bf(td[row*128 + k]);
  }
  for (int i = id0; i < 4096; i += stride){
    int tg = i >> 9, l = (i >> 3) & 63, j = i & 7;
    int c = tg*16 + (l & 15);
    float v = 0.f;
    if (l < 16 && j < 4) v = (j < 3) ? W_d1[c*3 + j] : b_d1[c];
    w1f[i] = f2bf(v);
  }
  for (int i = id0; i < 8192; i += stride){
    int tg = i >> 10, s = (i >> 9) & 1, l = (i >> 3) & 63, j = i & 7;
    int row = tg*16 + (l & 15), k = s*32 + (l >> 4)*8 + j;
    winf[i] = f2bf(W_in[row*64 + k]);
  }
  for (int o = id0; o < 128; o += stride){
    float acc = b_a[o];
    for (int c = 0; c < 128; ++c) acc += W_a[o*128 + c] * b_d2[c];
    ball[o] = acc;
  }
}

// ---------------- A: h = W_in x + b_in ; LN1 -> hn --------------------------
__global__ __launch_bounds__(256) void k_a(const float* __restrict__ x,
    const unsigned short* __restrict__ WINF, const float* __restrict__ b_in,
    const float* __restrict__ g1, const float* __restrict__ be1,
    float* __restrict__ H, unsigned short* __restrict__ HN){
  __shared__ unsigned short xT[64][72];
  int tid = threadIdx.x;
  int bb = blockIdx.x >> 6;
  int n0 = (blockIdx.x & 63) * 64;
  for (int i = tid; i < 4096; i += 256){
    int c = i >> 6, nn = i & 63;
    xT[nn][c] = f2bf(x[((size_t)(bb*64 + c))*4096 + n0 + nn]);
  }
  __syncthreads();
  int lane = tid & 63, w = tid >> 6, m16 = lane & 15, g = lane >> 4;
  const char* xb = (const char*)&xT[0][0];
  s8 a0 = *(const s8*)(xb + (w*16 + m16)*144 + 16*g);
  s8 a1 = *(const s8*)(xb + (w*16 + m16)*144 + 64 + 16*g);
  const f4 zf = {0.f, 0.f, 0.f, 0.f};
  f4 acc[8];
  #pragma unroll
  for (int t = 0; t < 8; ++t) acc[t] = zf;
  #pragma unroll
  for (int t = 0; t < 8; ++t){
    s8 b0 = *(const s8*)(WINF + ((size_t)(t*2 + 0)*64 + lane)*8);
    s8 b1 = *(const s8*)(WINF + ((size_t)(t*2 + 1)*64 + lane)*8);
    acc[t] = MFMA16(a0, b0, acc[t]);
    acc[t] = MFMA16(a1, b1, acc[t]);
  }
  float mean[4], rstd[4];
  #pragma unroll
  for (int r = 0; r < 4; ++r){
    float ls = 0.f, lq = 0.f;
    #pragma unroll
    for (int t = 0; t < 8; ++t){
      float v = acc[t][r] + b_in[t*16 + m16];
      ls += v; lq += v*v;
    }
    ls += __shfl_xor(ls, 1); ls += __shfl_xor(ls, 2); ls += __shfl_xor(ls, 4); ls += __shfl_xor(ls, 8);
    lq += __shfl_xor(lq, 1); lq += __shfl_xor(lq, 2); lq += __shfl_xor(lq, 4); lq += __shfl_xor(lq, 8);
    float mn = ls * (1.f/128.f);
    float vr = lq * (1.f/128.f) - mn*mn;
    mean[r] = mn;
    rstd[r] = rsqrtf(vr + 1e-5f);
  }
  int ptbase = blockIdx.x*64 + w*16;
  #pragma unroll
  for (int t = 0; t < 8; ++t){
    int o = t*16 + m16;
    float bi = b_in[o], gg = g1[o], be = be1[o];
    #pragma unroll
    for (int r = 0; r < 4; ++r){
      int pt = ptbase + 4*g + r;
      float v = acc[t][r] + bi;
      H[(size_t)pt*128 + o] = v;
      HN[(size_t)pt*128 + o] = f2bf((v - mean[r])*rstd[r]*gg + be);
    }
  }
}

// ---------------- generic data(A) x table(B) GEMM, K=128 -------------------
template<int MODE>
__global__ __launch_bounds__(256) void k_gemm(const unsigned short* __restrict__ A,
    const unsigned short* __restrict__ Btab, const float* __restrict__ bias,
    unsigned short* __restrict__ out){
  int lane = threadIdx.x & 63, w = threadIdx.x >> 6;
  int m0 = blockIdx.x*64 + w*16;
  int by = blockIdx.y;
  int m16 = lane & 15, g = lane >> 4;
  const f4 zf = {0.f, 0.f, 0.f, 0.f};
  f4 acc[8];
  #pragma unroll
  for (int t = 0; t < 8; ++t) acc[t] = zf;
  #pragma unroll
  for (int s = 0; s < 4; ++s){
    s8 af = *(const s8*)(A + ((size_t)(m0 + m16))*128 + s*32 + g*8);
    #pragma unroll
    for (int t = 0; t < 8; ++t){
      s8 bf = *(const s8*)(Btab + ((size_t)((by*8 + t)*4 + s)*64 + lane)*8);
      acc[t] = MFMA16(af, bf, acc[t]);
    }
  }
  #pragma unroll
  for (int t = 0; t < 8; ++t){
    int col = by*128 + t*16 + m16;
    #pragma unroll
    for (int r = 0; r < 4; ++r){
      int pt = m0 + 4*g + r;
      float v = acc[t][r];
      if (MODE == 0){
        int pos = (col < 128) ? 2*col : ((col < 256) ? 2*(col - 128) + 1 : col);
        out[(size_t)pt*384 + pos] = f2bf(v);
      } else {
        v = fmaxf(v + bias[col], 0.f);
        out[(size_t)pt*512 + col] = f2bf(v);
      }
    }
  }
}

// ---------------- F2: out(B,C,N) += W_f2 @ z^T + b_f2 ----------------------
__global__ __launch_bounds__(256) void k_f2(const unsigned short* __restrict__ wf2f,
    const unsigned short* __restrict__ Z, const float* __restrict__ b_f2,
    float* __restrict__ out){
  int lane = threadIdx.x & 63, w = threadIdx.x >> 6;
  int mt = blockIdx.x*4 + w;
  int p0 = blockIdx.y*128;
  int m16 = lane & 15, g = lane >> 4;
  const f4 zf = {0.f, 0.f, 0.f, 0.f};
  f4 acc[8];
  #pragma unroll
  for (int t = 0; t < 8; ++t) acc[t] = zf;
  #pragma unroll 4
  for (int s = 0; s < 16; ++s){
    s8 af = *(const s8*)(wf2f + ((size_t)(mt*16 + s)*64 + lane)*8);
    #pragma unroll
    for (int t = 0; t < 8; ++t){
      s8 bf = *(const s8*)(Z + (size_t)(p0 + t*16 + m16)*512 + s*32 + g*8);
      acc[t] = MFMA16(af, bf, acc[t]);
    }
  }
  #pragma unroll
  for (int t = 0; t < 8; ++t){
    #pragma unroll
    for (int r = 0; r < 4; ++r){
      int o = mt*16 + 4*g + r;
      int pt = p0 + t*16 + m16;
      int b = pt >> 12, n = pt & 4095;
      size_t ix = (((size_t)(b*128 + o)) << 12) | (unsigned)n;
      out[ix] += acc[t][r] + b_f2[o];
    }
  }
}

// ---------------- KNN: single-scan packed-key exact top-16 -----------------
// grid: 2048 = 8 batches x 256 tiles(16 queries); thread (q=tid&15, sub=tid>>4)
// scans [sub*256, sub*256+256). Init-64: 4x(sort16+merge16r) drain-free.
// Steady: 12x16 with imm-offset loads + buffered drains. 4-level merge tree.
// Plain launch bounds: R10's (256,8) cap forced 196MB of scratch spills.
__global__ __launch_bounds__(256) void k_knn(const float4* __restrict__ PP,
    int* __restrict__ IDXo){
  __shared__ __align__(16) char smem[17920];
  int tid = threadIdx.x;
  int b = blockIdx.x >> 8;
  int tile = blockIdx.x & 255;
  int q = tid & 15;
  int sub = tid >> 4;
  int qn = tile*16 + q;
  const float4* pb = PP + (size_t)b*4096;
  float4 me = pb[qn];
  const float4* cb = pb + (sub << 8);

  // ---- init-64: 4 chunks of 16, sorted + merged (exact r17 via discards) ----
  unsigned top32[16];
  unsigned r17 = 0xFFFFFFFFu;
  #pragma unroll
  for (int c = 0; c < 4; ++c){
    unsigned v[16];
    #pragma unroll
    for (int j = 0; j < 16; ++j){
      float4 cd = cb[c*16 + j];
      int m = (sub << 8) + c*16 + j;
      float dx = me.x-cd.x, dy = me.y-cd.y, dz = me.z-cd.z;
      unsigned key = (__builtin_bit_cast(unsigned, dx*dx+dy*dy+dz*dz) & 0xFFFFF000u) | (unsigned)m;
      v[j] = (m == qn) ? 0xFFFFFFFFu : key;
    }
    sort16_u32(v);
    if (c == 0){
      #pragma unroll
      for (int j = 0; j < 16; ++j) top32[j] = v[j];
    } else {
      merge16r(top32, v, r17);
    }
  }
  unsigned thr = top32[15];

  // ---- steady scan: cands 64..255, imm-offset loads, buffered drains ----
  int cnt = 0;
  unsigned* br32 = (unsigned*)(smem + tid*68);
  #pragma unroll 1
  for (int oo = 0; oo < 12; ++oo){
    const float4* ob = cb + 64 + oo*16;
    int mb = (sub << 8) + 64 + oo*16;
    #pragma unroll
    for (int jg = 0; jg < 4; ++jg){
      #pragma unroll
      for (int u = 0; u < 4; ++u){
        int j = jg*4 + u;
        float4 cd = ob[j];
        int m = mb + j;
        float dx = me.x-cd.x, dy = me.y-cd.y, dz = me.z-cd.z;
        unsigned key = (__builtin_bit_cast(unsigned, dx*dx+dy*dy+dz*dz) & 0xFFFFF000u) | (unsigned)m;
        if (m != qn){ if (key < thr){ br32[cnt] = key; ++cnt; } else r17 = min(r17, key); }
      }
      if (__any(cnt >= 13)) drainP(br32, cnt, top32, r17, thr);
    }
  }
  drainP(br32, cnt, top32, r17, thr);

  // ---- merge tree across the 16 subsets: rows of 17 u32 (16 keys + r17) ----
  unsigned* pub = (unsigned*)smem;
  #pragma unroll
  for (int step = 8; step >= 1; step >>= 1){
    __syncthreads();
    if (sub >= step && sub < 2*step){
      unsigned* row = pub + (size_t)((sub - step)*16 + q)*17;
      #pragma unroll
      for (int j = 0; j < 16; ++j) row[j] = top32[j];
      row[16] = r17;
    }
    __syncthreads();
    if (sub < step){
      unsigned other[16];
      unsigned* row = pub + (size_t)(sub*16 + q)*17;
      #pragma unroll
      for (int j = 0; j < 16; ++j) other[j] = row[j];
      r17 = min(r17, row[16]);
      merge16r(top32, other, r17);
    }
  }

  unsigned key16 = top32[15];
  bool flag = false;
  if (sub == 0){
    flag = ((r17 >> 12) - (key16 >> 12)) <= 1u;
    if (!flag){
      int* op = IDXo + ((size_t)(b*4096 + qn))*16;
      #pragma unroll
      for (int j = 0; j < 16; ++j) op[j] = (int)(top32[j] & 0xFFFu);
    }
  }

  // ---- rare exact f64 fixup (wave 0, cooperative per flagged query) ----
  if ((tid >> 6) == 0){
    int lane = tid & 63;
    unsigned long long flags = __ballot(flag);
    int* pcnt = (int*)(smem + 17408);
    unsigned* pool = (unsigned*)(smem + 17412);
    while (flags){
      int L = __ffsll((long long)flags) - 1;
      flags &= flags - 1;
      int qf = tile*16 + L;
      float qx = __shfl(me.x, L), qy = __shfl(me.y, L), qz = __shfl(me.z, L);
      unsigned k16 = __shfl(key16, L);
      unsigned t16 = k16 >> 12;
      unsigned bhi = (t16 >= 0xFFFFDu) ? 0xFFFFFFFFu : ((t16 + 2) << 12);
      if (lane == 0) atomicExch(pcnt, 0);
      #pragma unroll 4
      for (int it = 0; it < 64; ++it){
        int m = it*64 + lane;
        float4 cd = pb[m];
        float dx = qx-cd.x, dy = qy-cd.y, dz = qz-cd.z;
        unsigned bits = __builtin_bit_cast(unsigned, dx*dx+dy*dy+dz*dz);
        if (m != qf && bits < bhi){
          int s = atomicAdd(pcnt, 1);
          if (s < 64) pool[s] = (unsigned)m;
        }
      }
      int pn = atomicAdd(pcnt, 0);
      if (pn > 64) pn = 64;
      unsigned long long kk = ~0ull;
      if (lane < pn){
        int m = pool[lane];
        float4 cd = pb[m];
        double ddx = (double)qx - (double)cd.x;
        double ddy = (double)qy - (double)cd.y;
        double ddz = (double)qz - (double)cd.z;
        double d2 = ddx*ddx + ddy*ddy + ddz*ddz;
        kk = (__builtin_bit_cast(unsigned long long, d2) & ~0xFFFull) | (unsigned)m;
      }
      #pragma unroll
      for (int k2 = 2; k2 <= 64; k2 <<= 1){
        #pragma unroll
        for (int j = k2 >> 1; j >= 1; j >>= 1){
          unsigned long long o = __shfl_xor(kk, j);
          bool up = ((lane & k2) == 0);
          bool keepmin = (((lane & j) == 0) == up);
          unsigned long long mn = kk < o ? kk : o;
          unsigned long long mx = kk < o ? o : kk;
          kk = keepmin ? mn : mx;
        }
      }
      if (lane < 16)
        IDXo[((size_t)(b*4096 + qf))*16 + lane] = (int)(unsigned)(kk & 0xFFFull);
    }
  }
}

// ---------------- ATTN: per-point fused kNN attention ----------------------
// 2 points/wave. LDS per wave: 4608B kv region [2 q][16 m][72 u16] (144B
// rows); t1 scratch (4KB) aliases it during setup. No softmax max-subtract.
__global__ __launch_bounds__(256) void k_attn(const float* __restrict__ pcoord,
    const int* __restrict__ IDX, const unsigned short* __restrict__ QKV,
    const unsigned short* __restrict__ W1F, const unsigned short* __restrict__ WD2F,
    const unsigned short* __restrict__ WDAF, const float* __restrict__ b_d2,
    const float* __restrict__ BALL, unsigned short* __restrict__ Y){
  __shared__ __align__(16) char smem[18432];
  __shared__ int idx_sh[4][2][16];
  int tid = threadIdx.x;
  int w = tid >> 6, lane = tid & 63;
  int m16 = lane & 15, g = lane >> 4;
  int P0 = blockIdx.x*8 + w*2;
  char* wbase = smem + w*4608;
  const f4 zf = {0.f, 0.f, 0.f, 0.f};
  if (lane < 16){
    #pragma unroll
    for (int q = 0; q < 2; ++q) idx_sh[w][q][lane] = IDX[(size_t)(P0 + q)*16 + lane];
  }
  // ---- setup: a[q][s] = A-frags of relu(rel_aug @ W1aug^T), t1 in alias ----
  unsigned short* t1s = (unsigned short*)wbase;
  s8 a[2][4];
  #pragma unroll
  for (int q = 0; q < 2; ++q){
    int pt = P0 + q;
    int bq = pt >> 12, nn = pt & 4095;
    const float* pb = pcoord + (size_t)bq*3*4096;
    s8 arel = {0,0,0,0,0,0,0,0};
    if (lane < 16){
      int jn = idx_sh[w][q][m16];
      float rx = pb[nn] - pb[jn];
      float ry = pb[4096 + nn] - pb[4096 + jn];
      float rz = pb[8192 + nn] - pb[8192 + jn];
      arel[0] = (short)f2bf(rx); arel[1] = (short)f2bf(ry);
      arel[2] = (short)f2bf(rz); arel[3] = (short)0x3F80;
    }
    f4 t1a[8];
    #pragma unroll
    for (int t = 0; t < 8; ++t){
      s8 bw = *(const s8*)(W1F + ((size_t)t*64 + lane)*8);
      t1a[t] = MFMA16(arel, bw, zf);
    }
    #pragma unroll
    for (int t = 0; t < 8; ++t){
      int c = t*16 + m16;
      #pragma unroll
      for (int r = 0; r < 4; ++r){
        int m = 4*g + r;
        int byt = (m*256 + c*2) ^ ((m & 7) << 4);
        t1s[byt >> 1] = f2bf(fmaxf(t1a[t][r], 0.f));
      }
    }
    const char* t1b = (const char*)t1s;
    #pragma unroll
    for (int s = 0; s < 4; ++s){
      int byt = (m16*256 + 64*s + 16*g) ^ ((m16 & 7) << 4);
      a[q][s] = *(const s8*)(t1b + byt);
    }
  }
  // ---- main: 4 passes over o-quarters ----
  #pragma unroll 1
  for (int pass = 0; pass < 4; ++pass){
    // WAR fence: previous pass's kv reads (or t1 reads) drain before overwrite
    asm volatile("s_waitcnt lgkmcnt(0)" ::: "memory");
    __builtin_amdgcn_sched_barrier(0);
    // gather this pass's kv columns + qa row
    uint4 gk[2][2];
    float qv[2];
    #pragma unroll
    for (int q = 0; q < 2; ++q){
      int pt = P0 + q, bq = pt >> 12;
      #pragma unroll
      for (int i2 = 0; i2 < 2; ++i2){
        int mm = i2*8 + (lane >> 3);
        int jn = idx_sh[w][q][mm];
        gk[q][i2] = *(const uint4*)((const char*)QKV
            + ((size_t)(bq*4096 + jn))*768 + pass*128 + (lane & 7)*16);
      }
      qv[q] = bf2f(QKV[(size_t)pt*384 + 256 + pass*32 + (lane & 31)]);
    }
    #pragma unroll
    for (int q = 0; q < 2; ++q){
      #pragma unroll
      for (int i2 = 0; i2 < 2; ++i2)
        *(uint4*)(wbase + q*2304 + (i2*8 + (lane >> 3))*144 + (lane & 7)*16) = gk[q][i2];
    }
    #pragma unroll
    for (int tl = 0; tl < 2; ++tl){
      int tg = pass*2 + tl;
      f4 dacc[2], lacc[2];
      #pragma unroll
      for (int q = 0; q < 2; ++q){ dacc[q] = zf; lacc[q] = zf; }
      #pragma unroll
      for (int s = 0; s < 4; ++s){
        s8 wd2 = *(const s8*)(WD2F + ((size_t)(tg*4 + s)*64 + lane)*8);
        s8 wda = *(const s8*)(WDAF + ((size_t)(tg*4 + s)*64 + lane)*8);
        #pragma unroll
        for (int q = 0; q < 2; ++q){
          dacc[q] = MFMA16(a[q][s], wd2, dacc[q]);
          lacc[q] = MFMA16(a[q][s], wda, lacc[q]);
        }
      }
      int col = tg*16 + m16;
      float bd2c = b_d2[col];
      float ballc = BALL[col];
      #pragma unroll
      for (int q = 0; q < 2; ++q){
        int pt = P0 + q;
        float qbase = __shfl(qv[q], tl*16 + m16) + ballc;
        float lg[4], dd[4], vv[4];
        #pragma unroll
        for (int r = 0; r < 4; ++r){
          int m = 4*g + r;
          unsigned kvp = *(const unsigned*)(wbase + q*2304 + m*144 + (tl*16 + m16)*4);
          float ka = bf2f((unsigned short)(kvp & 0xFFFFu));
          vv[r] = bf2f((unsigned short)(kvp >> 16));
          lg[r] = lacc[q][r] + qbase - ka;
          dd[r] = dacc[q][r] + bd2c;
        }
        // no max-subtraction: logits are O(10), overflow at 88
        float e0 = __expf(lg[0]), e1 = __expf(lg[1]);
        float e2 = __expf(lg[2]), e3 = __expf(lg[3]);
        float ss = e0 + e1 + e2 + e3;
        ss += __shfl_xor(ss, 16); ss += __shfl_xor(ss, 32);
        float inv = 1.f / ss;
        float yp = e0*(vv[0] + dd[0]) + e1*(vv[1] + dd[1])
                 + e2*(vv[2] + dd[2]) + e3*(vv[3] + dd[3]);
        yp *= inv;
        yp += __shfl_xor(yp, 16); yp += __shfl_xor(yp, 32);
        if (lane < 16) Y[(size_t)pt*128 + col] = f2bf(yp);
      }
    }
  }
}

// ---------------- D1: h2 = h + y ; d_out = h2 ; hn2 = LN2(h2) ---------------
__global__ __launch_bounds__(256) void k_d1(const float* __restrict__ H,
    const unsigned short* __restrict__ Y, const float* __restrict__ g2,
    const float* __restrict__ be2, float* __restrict__ outp,
    unsigned short* __restrict__ HN2){
  __shared__ float tile[128*65];
  int tid = threadIdx.x;
  int w = tid >> 6, lane = tid & 63;
  int pt16 = lane & 15, g = lane >> 4;
  int n64 = w*16 + pt16;
  int ptbase = blockIdx.x * 64;
  int pt = ptbase + n64;
  int c0 = g*32;
  const float4* h4 = (const float4*)(H + (size_t)pt*128 + c0);
  const uint4*  y4 = (const uint4*)((const char*)Y + (size_t)pt*256 + (size_t)c0*2);
  float h2[32];
  float ls = 0.f, lq = 0.f;
  #pragma unroll
  for (int i = 0; i < 4; ++i){
    float4 ha = h4[2*i], hb = h4[2*i + 1];
    uint4 yv = y4[i];
    float v0 = ha.x + bf2f((unsigned short)(yv.x & 0xFFFFu));
    float v1 = ha.y + bf2f((unsigned short)(yv.x >> 16));
    float v2 = ha.z + bf2f((unsigned short)(yv.y & 0xFFFFu));
    float v3 = ha.w + bf2f((unsigned short)(yv.y >> 16));
    float v4 = hb.x + bf2f((unsigned short)(yv.z & 0xFFFFu));
    float v5 = hb.y + bf2f((unsigned short)(yv.z >> 16));
    float v6 = hb.z + bf2f((unsigned short)(yv.w & 0xFFFFu));
    float v7 = hb.w + bf2f((unsigned short)(yv.w >> 16));
    h2[8*i+0]=v0; h2[8*i+1]=v1; h2[8*i+2]=v2; h2[8*i+3]=v3;
    h2[8*i+4]=v4; h2[8*i+5]=v5; h2[8*i+6]=v6; h2[8*i+7]=v7;
    ls += v0+v1+v2+v3+v4+v5+v6+v7;
    lq += v0*v0+v1*v1+v2*v2+v3*v3+v4*v4+v5*v5+v6*v6+v7*v7;
  }
  ls += __shfl_xor(ls, 16); ls += __shfl_xor(ls, 32);
  lq += __shfl_xor(lq, 16); lq += __shfl_xor(lq, 32);
  float mn = ls * (1.f/128.f);
  float vr = lq * (1.f/128.f) - mn*mn;
  float rs = rsqrtf(vr + 1e-5f);
  const float4* g4  = (const float4*)(g2 + c0);
  const float4* be4 = (const float4*)(be2 + c0);
  #pragma unroll
  for (int i = 0; i < 4; ++i){
    float4 ga = g4[2*i], gb = g4[2*i+1], ba = be4[2*i], bb2 = be4[2*i+1];
    unsigned uu[4];
    uu[0] = (unsigned)f2bf((h2[8*i+0]-mn)*rs*ga.x + ba.x)
          | ((unsigned)f2bf((h2[8*i+1]-mn)*rs*ga.y + ba.y) << 16);
    uu[1] = (unsigned)f2bf((h2[8*i+2]-mn)*rs*ga.z + ba.z)
          | ((unsigned)f2bf((h2[8*i+3]-mn)*rs*ga.w + ba.w) << 16);
    uu[2] = (unsigned)f2bf((h2[8*i+4]-mn)*rs*gb.x + bb2.x)
          | ((unsigned)f2bf((h2[8*i+5]-mn)*rs*gb.y + bb2.y) << 16);
    uu[3] = (unsigned)f2bf((h2[8*i+6]-mn)*rs*gb.z + bb2.z)
          | ((unsigned)f2bf((h2[8*i+7]-mn)*rs*gb.w + bb2.w) << 16);
    *(uint4*)((char*)HN2 + (size_t)pt*256 + (size_t)c0*2 + i*16)
        = make_uint4(uu[0], uu[1], uu[2], uu[3]);
  }
  int swz = g << 4;
  #pragma unroll
  for (int k = 0; k < 32; ++k)
    tile[(c0 + k)*65 + (n64 ^ swz)] = h2[k];
  __syncthreads();
  int bb = ptbase >> 12;
  int nb = ptbase & 4095;
  #pragma unroll 8
  for (int k = 0; k < 32; ++k){
    int c = w*32 + k;
    float v = tile[c*65 + (lane ^ ((((unsigned)c >> 5) & 3) << 4))];
    outp[(((size_t)(bb*128 + c)) << 12) | (unsigned)(nb + lane)] = v;
  }
}

// ---------------------------------------------------------------------------
extern "C" void kernel_launch(void* const* d_in, const int* in_sizes, int n_in,
                              void* d_out, int out_size, void* d_ws, size_t ws_size,
                              hipStream_t stream){
  const float* x    = (const float*)d_in[0];
  const float* p    = (const float*)d_in[1];
  const float* W_in = (const float*)d_in[2];
  const float* b_in = (const float*)d_in[3];
  const float* W_q  = (const float*)d_in[4];
  const float* W_k  = (const float*)d_in[5];
  const float* W_v  = (const float*)d_in[6];
  const float* W_d1 = (const float*)d_in[7];
  const float* b_d1 = (const float*)d_in[8];
  const float* W_d2 = (const float*)d_in[9];
  const float* b_d2 = (const float*)d_in[10];
  const float* W_a  = (const float*)d_in[11];
  const float* b_a  = (const float*)d_in[12];
  const float* g1   = (const float*)d_in[13];
  const float* be1  = (const float*)d_in[14];
  const float* g2   = (const float*)d_in[15];
  const float* be2  = (const float*)d_in[16];
  const float* W_f1 = (const float*)d_in[17];
  const float* b_f1 = (const float*)d_in[18];
  const float* W_f2 = (const float*)d_in[19];
  const float* b_f2 = (const float*)d_in[20];
  float* out = (float*)d_out;
  char* ws = (char*)d_ws;

  float*          H    = (float*)(ws + 0);
  unsigned short* HN   = (unsigned short*)(ws + 16777216);
  unsigned short* QKV  = (unsigned short*)(ws + 25165824);
  unsigned short* Z    = (unsigned short*)(ws + 16777216);  // alias HN+QKV
  unsigned short* Y    = (unsigned short*)(ws + 50331648);
  unsigned short* HN2  = (unsigned short*)(ws + 58720256);
  int*            IDX  = (int*)(ws + 67108864);
  float4*         PP   = (float4*)(ws + 69206016);
  char* tab = ws + 69730304;
  unsigned short* WCATF = (unsigned short*)(tab + 0);
  unsigned short* WF1F  = (unsigned short*)(tab + 98304);
  unsigned short* WF2F  = (unsigned short*)(tab + 229376);
  unsigned short* WD2F  = (unsigned short*)(tab + 360448);
  unsigned short* WDAF  = (unsigned short*)(tab + 393216);
  unsigned short* W1F   = (unsigned short*)(tab + 425984);
  unsigned short* WINF  = (unsigned short*)(tab + 434176);
  float*          BALL  = (float*)(tab + 450560);
  float*          TK    = (float*)(tab + 451072);
  float*          TQ    = (float*)(tab + 516608);
  float*          TD    = (float*)(tab + 582144);

  k_p1<<<dim3(384), dim3(128), 0, stream>>>(W_a, W_k, W_q, W_d2, TK, TQ, TD);
  k_pack<<<dim3(256), dim3(256), 0, stream>>>(p, W_v, W_d1, b_d1, W_in, W_f1, W_f2,
      W_a, b_a, b_d2, W_d2, TK, TQ, TD,
      PP, WCATF, WF1F, WF2F, WD2F, WDAF, W1F, WINF, BALL);
  k_knn<<<dim3(2048), dim3(256), 0, stream>>>(PP, IDX);
  k_a<<<dim3(512), dim3(256), 0, stream>>>(x, WINF, b_in, g1, be1, H, HN);
  k_gemm<0><<<dim3(512, 3), dim3(256), 0, stream>>>(HN, WCATF, nullptr, QKV);
  k_attn<<<dim3(4096), dim3(256), 0, stream>>>(p, IDX, QKV, W1F, WD2F, WDAF, b_d2, BALL, Y);
  k_d1<<<dim3(512), dim3(256), 0, stream>>>(H, Y, g2, be2, out, HN2);
  k_gemm<1><<<dim3(512, 4), dim3(256), 0, stream>>>(HN2, WF1F, b_f1, Z);
  k_f2<<<dim3(2, 256), dim3(256), 0, stream>>>(WF2F, Z, b_f2, out);
}

// Round 12
// 329.248 us; speedup vs baseline: 1.1211x; 1.0690x over previous
//
#include <hip/hip_runtime.h>
#include <stdint.h>

// ---------------------------------------------------------------------------
// PTBlock fused implementation (B=8, Cin=64, C=128, N=4096, k=16, HID=512)
// R12 changes (R11: init-64's serial sorts cost more than the drains they
// saved AND halving cands/thread duplicated fixed costs):
//  - k_knn back to 8 subsets x 512 cands/thread (R9 shape, 128us proven)
//  - init-16 only: one sort16 seeds thr (kills thr=inf drain burst)
//  - 128-thr blocks (16q x 8sub), grid 2048, LDS 9KB -> 8+ blocks/CU for TLP
//  - plain launch bounds (no forced caps — R7/R10 spill lessons)
// ---------------------------------------------------------------------------

typedef __attribute__((ext_vector_type(8))) short s8;
typedef __attribute__((ext_vector_type(4))) float f4;

#define MFMA16(a,b,c) __builtin_amdgcn_mfma_f32_16x16x32_bf16(a,b,c,0,0,0)

__device__ __forceinline__ float bf2f(unsigned short u){
  unsigned x = ((unsigned)u) << 16; return __builtin_bit_cast(float, x);
}
__device__ __forceinline__ unsigned short f2bf(float f){
  unsigned x = __builtin_bit_cast(unsigned, f);
  x = x + 0x7FFFu + ((x >> 16) & 1u);
  return (unsigned short)(x >> 16);
}

// ---------------- u32-key sorting helpers ----------------------------------
__device__ __forceinline__ void ce32(unsigned &a, unsigned &b){
  unsigned mn = min(a, b), mx = max(a, b);
  a = mn; b = mx;
}
__device__ __forceinline__ void sort16_u32(unsigned v[16]){
  #pragma unroll
  for (int p = 1; p < 16; p <<= 1){
    #pragma unroll
    for (int k = p; k >= 1; k >>= 1){
      #pragma unroll
      for (int j = k % p; j + k < 16; j += 2*k){
        #pragma unroll
        for (int i = 0; i < k; ++i){
          if (i + j + k < 16){
            if (((i+j) / (2*p)) == ((i+j+k) / (2*p))) ce32(v[i+j], v[i+j+k]);
          }
        }
      }
    }
  }
}
__device__ __forceinline__ void bitonic16_u32(unsigned v[16]){
  #pragma unroll
  for (int k = 8; k >= 1; k >>= 1){
    #pragma unroll
    for (int i = 0; i < 16; ++i){
      if ((i & k) == 0) ce32(v[i], v[i | k]);
    }
  }
}
// merge two sorted-asc 16-seqs; top<-16 smallest; r17 <- min(r17, 17th of union)
__device__ __forceinline__ void merge16r(unsigned top[16], const unsigned w[16],
                                         unsigned &r17){
  unsigned t[16], m17 = 0xFFFFFFFFu;
  #pragma unroll
  for (int i = 0; i < 16; ++i){
    unsigned a = top[i], b = w[15 - i];
    t[i] = min(a, b);
    m17 = min(m17, max(a, b));
  }
  bitonic16_u32(t);
  #pragma unroll
  for (int i = 0; i < 16; ++i) top[i] = t[i];
  r17 = min(r17, m17);
}
__device__ __forceinline__ void drainP(unsigned* br, int &cnt, unsigned top[16],
                                       unsigned &r17, unsigned &thr){
  unsigned v[16];
  #pragma unroll
  for (int j = 0; j < 16; ++j){
    unsigned t = br[j];
    v[j] = (j < cnt) ? t : 0xFFFFFFFFu;
  }
  cnt = 0;
  sort16_u32(v);
  merge16r(top, v, r17);
  thr = top[15];
}

// ---------------- P1: Wak = Wa@Wk, Waq = Wa@Wq, Wda = Wa@Wd2 ---------------
__global__ __launch_bounds__(128) void k_p1(const float* __restrict__ W_a,
    const float* __restrict__ W_k, const float* __restrict__ W_q, const float* __restrict__ W_d2,
    float* __restrict__ tk, float* __restrict__ tq, float* __restrict__ td){
  int which = blockIdx.x >> 7, row = blockIdx.x & 127, c = threadIdx.x;
  const float* X = (which == 0) ? W_k : ((which == 1) ? W_q : W_d2);
  float* O = (which == 0) ? tk : ((which == 1) ? tq : td);
  float acc = 0.f;
  #pragma unroll 8
  for (int i = 0; i < 128; ++i) acc += W_a[row*128 + i] * X[i*128 + c];
  O[row*128 + c] = acc;
}

// ---------------- P2: pack fragment tables, pp, ball -----------------------
__global__ __launch_bounds__(256) void k_pack(
    const float* __restrict__ p, const float* __restrict__ W_v,
    const float* __restrict__ W_d1, const float* __restrict__ b_d1,
    const float* __restrict__ W_in, const float* __restrict__ W_f1, const float* __restrict__ W_f2,
    const float* __restrict__ W_a, const float* __restrict__ b_a, const float* __restrict__ b_d2,
    const float* __restrict__ W_d2,
    const float* __restrict__ tk, const float* __restrict__ tq, const float* __restrict__ td,
    float4* __restrict__ pp, unsigned short* __restrict__ wcatf, unsigned short* __restrict__ wf1f,
    unsigned short* __restrict__ wf2f, unsigned short* __restrict__ wd2f,
    unsigned short* __restrict__ wdaf, unsigned short* __restrict__ w1f,
    unsigned short* __restrict__ winf, float* __restrict__ ball){
  int id0 = blockIdx.x * blockDim.x + threadIdx.x;
  int stride = gridDim.x * blockDim.x;
  for (int i = id0; i < 32768; i += stride){
    int b = i >> 12, m = i & 4095;
    float xx = p[(b*3 + 0)*4096 + m];
    float yy = p[(b*3 + 1)*4096 + m];
    float zz = p[(b*3 + 2)*4096 + m];
    pp[i] = float4{xx, yy, zz, xx*xx + yy*yy + zz*zz};
  }
  for (int i = id0; i < 49152; i += stride){
    int tg = i >> 11, s = (i >> 9) & 3, l = (i >> 3) & 63, j = i & 7;
    int row = tg*16 + (l & 15), k = s*32 + (l >> 4)*8 + j;
    float v;
    if (row < 128) v = tk[row*128 + k];
    else if (row < 256) v = W_v[(row - 128)*128 + k];
    else v = tq[(row - 256)*128 + k];
    wcatf[i] = f2bf(v);
  }
  for (int i = id0; i < 65536; i += stride){
    int tg = i >> 11, s = (i >> 9) & 3, l = (i >> 3) & 63, j = i & 7;
    int row = tg*16 + (l & 15), k = s*32 + (l >> 4)*8 + j;
    wf1f[i] = f2bf(W_f1[row*128 + k]);
  }
  for (int i = id0; i < 65536; i += stride){
    int mt = i >> 13, s = (i >> 9) & 15, l = (i >> 3) & 63, j = i & 7;
    int row = mt*16 + (l & 15), k = s*32 + (l >> 4)*8 + j;
    wf2f[i] = f2bf(W_f2[row*512 + k]);
  }
  for (int i = id0; i < 16384; i += stride){
    int tg = i >> 11, s = (i >> 9) & 3, l = (i >> 3) & 63, j = i & 7;
    int row = tg*16 + (l & 15), k = s*32 + (l >> 4)*8 + j;
    wd2f[i] = f2bf(W_d2[row*128 + k]);
  }
  for (int i = id0; i < 16384; i += stride){
    int tg = i >> 11, s = (i >> 9) & 3, l = (i >> 3) & 63, j = i & 7;
    int row = tg*16 + (l & 15), k = s*32 + (l >> 4)*8 + j;
    wdaf[i] = f2bf(td[row*128 + k]);
  }
  for (int i = id0; i < 4096; i += stride){
    int tg = i >> 9, l = (i >> 3) & 63, j = i & 7;
    int c = tg*16 + (l & 15);
    float v = 0.f;
    if (l < 16 && j < 4) v = (j < 3) ? W_d1[c*3 + j] : b_d1[c];
    w1f[i] = f2bf(v);
  }
  for (int i = id0; i < 8192; i += stride){
    int tg = i >> 10, s = (i >> 9) & 1, l = (i >> 3) & 63, j = i & 7;
    int row = tg*16 + (l & 15), k = s*32 + (l >> 4)*8 + j;
    winf[i] = f2bf(W_in[row*64 + k]);
  }
  for (int o = id0; o < 128; o += stride){
    float acc = b_a[o];
    for (int c = 0; c < 128; ++c) acc += W_a[o*128 + c] * b_d2[c];
    ball[o] = acc;
  }
}

// ---------------- A: h = W_in x + b_in ; LN1 -> hn --------------------------
__global__ __launch_bounds__(256) void k_a(const float* __restrict__ x,
    const unsigned short* __restrict__ WINF, const float* __restrict__ b_in,
    const float* __restrict__ g1, const float* __restrict__ be1,
    float* __restrict__ H, unsigned short* __restrict__ HN){
  __shared__ unsigned short xT[64][72];
  int tid = threadIdx.x;
  int bb = blockIdx.x >> 6;
  int n0 = (blockIdx.x & 63) * 64;
  for (int i = tid; i < 4096; i += 256){
    int c = i >> 6, nn = i & 63;
    xT[nn][c] = f2bf(x[((size_t)(bb*64 + c))*4096 + n0 + nn]);
  }
  __syncthreads();
  int lane = tid & 63, w = tid >> 6, m16 = lane & 15, g = lane >> 4;
  const char* xb = (const char*)&xT[0][0];
  s8 a0 = *(const s8*)(xb + (w*16 + m16)*144 + 16*g);
  s8 a1 = *(const s8*)(xb + (w*16 + m16)*144 + 64 + 16*g);
  const f4 zf = {0.f, 0.f, 0.f, 0.f};
  f4 acc[8];
  #pragma unroll
  for (int t = 0; t < 8; ++t) acc[t] = zf;
  #pragma unroll
  for (int t = 0; t < 8; ++t){
    s8 b0 = *(const s8*)(WINF + ((size_t)(t*2 + 0)*64 + lane)*8);
    s8 b1 = *(const s8*)(WINF + ((size_t)(t*2 + 1)*64 + lane)*8);
    acc[t] = MFMA16(a0, b0, acc[t]);
    acc[t] = MFMA16(a1, b1, acc[t]);
  }
  float mean[4], rstd[4];
  #pragma unroll
  for (int r = 0; r < 4; ++r){
    float ls = 0.f, lq = 0.f;
    #pragma unroll
    for (int t = 0; t < 8; ++t){
      float v = acc[t][r] + b_in[t*16 + m16];
      ls += v; lq += v*v;
    }
    ls += __shfl_xor(ls, 1); ls += __shfl_xor(ls, 2); ls += __shfl_xor(ls, 4); ls += __shfl_xor(ls, 8);
    lq += __shfl_xor(lq, 1); lq += __shfl_xor(lq, 2); lq += __shfl_xor(lq, 4); lq += __shfl_xor(lq, 8);
    float mn = ls * (1.f/128.f);
    float vr = lq * (1.f/128.f) - mn*mn;
    mean[r] = mn;
    rstd[r] = rsqrtf(vr + 1e-5f);
  }
  int ptbase = blockIdx.x*64 + w*16;
  #pragma unroll
  for (int t = 0; t < 8; ++t){
    int o = t*16 + m16;
    float bi = b_in[o], gg = g1[o], be = be1[o];
    #pragma unroll
    for (int r = 0; r < 4; ++r){
      int pt = ptbase + 4*g + r;
      float v = acc[t][r] + bi;
      H[(size_t)pt*128 + o] = v;
      HN[(size_t)pt*128 + o] = f2bf((v - mean[r])*rstd[r]*gg + be);
    }
  }
}

// ---------------- generic data(A) x table(B) GEMM, K=128 -------------------
template<int MODE>
__global__ __launch_bounds__(256) void k_gemm(const unsigned short* __restrict__ A,
    const unsigned short* __restrict__ Btab, const float* __restrict__ bias,
    unsigned short* __restrict__ out){
  int lane = threadIdx.x & 63, w = threadIdx.x >> 6;
  int m0 = blockIdx.x*64 + w*16;
  int by = blockIdx.y;
  int m16 = lane & 15, g = lane >> 4;
  const f4 zf = {0.f, 0.f, 0.f, 0.f};
  f4 acc[8];
  #pragma unroll
  for (int t = 0; t < 8; ++t) acc[t] = zf;
  #pragma unroll
  for (int s = 0; s < 4; ++s){
    s8 af = *(const s8*)(A + ((size_t)(m0 + m16))*128 + s*32 + g*8);
    #pragma unroll
    for (int t = 0; t < 8; ++t){
      s8 bf = *(const s8*)(Btab + ((size_t)((by*8 + t)*4 + s)*64 + lane)*8);
      acc[t] = MFMA16(af, bf, acc[t]);
    }
  }
  #pragma unroll
  for (int t = 0; t < 8; ++t){
    int col = by*128 + t*16 + m16;
    #pragma unroll
    for (int r = 0; r < 4; ++r){
      int pt = m0 + 4*g + r;
      float v = acc[t][r];
      if (MODE == 0){
        int pos = (col < 128) ? 2*col : ((col < 256) ? 2*(col - 128) + 1 : col);
        out[(size_t)pt*384 + pos] = f2bf(v);
      } else {
        v = fmaxf(v + bias[col], 0.f);
        out[(size_t)pt*512 + col] = f2bf(v);
      }
    }
  }
}

// ---------------- F2: out(B,C,N) += W_f2 @ z^T + b_f2 ----------------------
__global__ __launch_bounds__(256) void k_f2(const unsigned short* __restrict__ wf2f,
    const unsigned short* __restrict__ Z, const float* __restrict__ b_f2,
    float* __restrict__ out){
  int lane = threadIdx.x & 63, w = threadIdx.x >> 6;
  int mt = blockIdx.x*4 + w;
  int p0 = blockIdx.y*128;
  int m16 = lane & 15, g = lane >> 4;
  const f4 zf = {0.f, 0.f, 0.f, 0.f};
  f4 acc[8];
  #pragma unroll
  for (int t = 0; t < 8; ++t) acc[t] = zf;
  #pragma unroll 4
  for (int s = 0; s < 16; ++s){
    s8 af = *(const s8*)(wf2f + ((size_t)(mt*16 + s)*64 + lane)*8);
    #pragma unroll
    for (int t = 0; t < 8; ++t){
      s8 bf = *(const s8*)(Z + (size_t)(p0 + t*16 + m16)*512 + s*32 + g*8);
      acc[t] = MFMA16(af, bf, acc[t]);
    }
  }
  #pragma unroll
  for (int t = 0; t < 8; ++t){
    #pragma unroll
    for (int r = 0; r < 4; ++r){
      int o = mt*16 + 4*g + r;
      int pt = p0 + t*16 + m16;
      int b = pt >> 12, n = pt & 4095;
      size_t ix = (((size_t)(b*128 + o)) << 12) | (unsigned)n;
      out[ix] += acc[t][r] + b_f2[o];
    }
  }
}

// ---------------- KNN: single-scan packed-key exact top-16 -----------------
// grid: 2048 = 8 batches x 256 tiles(16 queries); 128 thr (q=tid&15, sub=tid>>4)
// each thread scans [sub*512, sub*512+512). Init-16: one sort16 seeds thr.
// Steady: pipelined groups of 4 + buffered drains. 3-level merge tree.
__global__ __launch_bounds__(128) void k_knn(const float4* __restrict__ PP,
    int* __restrict__ IDXo){
  __shared__ __align__(16) char smem[9216];
  int tid = threadIdx.x;
  int b = blockIdx.x >> 8;
  int tile = blockIdx.x & 255;
  int q = tid & 15;
  int sub = tid >> 4;
  int qn = tile*16 + q;
  const float4* pb = PP + (size_t)b*4096;
  float4 me = pb[qn];
  int base = sub << 9;

  unsigned* br32 = (unsigned*)(smem + tid*68);

  // ---- init-16: first 16 cands sorted -> top32 seed (no rejects/discards) --
  unsigned top32[16];
  {
    unsigned v[16];
    #pragma unroll
    for (int j = 0; j < 16; ++j){
      float4 cd = pb[base + j];
      int m = base + j;
      float dx = me.x-cd.x, dy = me.y-cd.y, dz = me.z-cd.z;
      unsigned key = (__builtin_bit_cast(unsigned, dx*dx+dy*dy+dz*dz) & 0xFFFFF000u) | (unsigned)m;
      v[j] = (m == qn) ? 0xFFFFFFFFu : key;
    }
    sort16_u32(v);
    #pragma unroll
    for (int j = 0; j < 16; ++j) top32[j] = v[j];
  }
  unsigned r17 = 0xFFFFFFFFu;
  unsigned thr = top32[15];
  int cnt = 0;

  // ---- steady scan: cands 16..511, software-pipelined groups of 4 ----
  float4 c0 = pb[base+16], c1 = pb[base+17], c2 = pb[base+18], c3 = pb[base+19];
  #pragma unroll 1
  for (int ii = 4; ii < 128; ++ii){
    float4 d0 = c0, d1 = c1, d2v = c2, d3 = c3;
    int nxt = (ii + 1 < 128) ? (ii + 1) : 4;
    int nb = base + (nxt << 2);
    c0 = pb[nb+0]; c1 = pb[nb+1]; c2 = pb[nb+2]; c3 = pb[nb+3];
    int m0 = base + ii*4;
    {
      float dx = me.x-d0.x, dy = me.y-d0.y, dz = me.z-d0.z;
      unsigned key = (__builtin_bit_cast(unsigned, dx*dx+dy*dy+dz*dz) & 0xFFFFF000u) | (unsigned)m0;
      if (m0 != qn){ if (key < thr){ br32[cnt] = key; ++cnt; } else r17 = min(r17, key); }
    }
    {
      float dx = me.x-d1.x, dy = me.y-d1.y, dz = me.z-d1.z;
      unsigned key = (__builtin_bit_cast(unsigned, dx*dx+dy*dy+dz*dz) & 0xFFFFF000u) | (unsigned)(m0+1);
      if (m0+1 != qn){ if (key < thr){ br32[cnt] = key; ++cnt; } else r17 = min(r17, key); }
    }
    {
      float dx = me.x-d2v.x, dy = me.y-d2v.y, dz = me.z-d2v.z;
      unsigned key = (__builtin_bit_cast(unsigned, dx*dx+dy*dy+dz*dz) & 0xFFFFF000u) | (unsigned)(m0+2);
      if (m0+2 != qn){ if (key < thr){ br32[cnt] = key; ++cnt; } else r17 = min(r17, key); }
    }
    {
      float dx = me.x-d3.x, dy = me.y-d3.y, dz = me.z-d3.z;
      unsigned key = (__builtin_bit_cast(unsigned, dx*dx+dy*dy+dz*dz) & 0xFFFFF000u) | (unsigned)(m0+3);
      if (m0+3 != qn){ if (key < thr){ br32[cnt] = key; ++cnt; } else r17 = min(r17, key); }
    }
    if (__any(cnt >= 13)) drainP(br32, cnt, top32, r17, thr);
  }
  drainP(br32, cnt, top32, r17, thr);

  // ---- merge tree across the 8 subsets: rows of 17 u32 (16 keys + r17) ----
  unsigned* pub = (unsigned*)smem;
  #pragma unroll
  for (int step = 4; step >= 1; step >>= 1){
    __syncthreads();
    if (sub >= step && sub < 2*step){
      unsigned* row = pub + (size_t)((sub - step)*16 + q)*17;
      #pragma unroll
      for (int j = 0; j < 16; ++j) row[j] = top32[j];
      row[16] = r17;
    }
    __syncthreads();
    if (sub < step){
      unsigned other[16];
      unsigned* row = pub + (size_t)(sub*16 + q)*17;
      #pragma unroll
      for (int j = 0; j < 16; ++j) other[j] = row[j];
      r17 = min(r17, row[16]);
      merge16r(top32, other, r17);
    }
  }

  unsigned key16 = top32[15];
  bool flag = false;
  if (sub == 0){
    flag = ((r17 >> 12) - (key16 >> 12)) <= 1u;
    if (!flag){
      int* op = IDXo + ((size_t)(b*4096 + qn))*16;
      #pragma unroll
      for (int j = 0; j < 16; ++j) op[j] = (int)(top32[j] & 0xFFFu);
    }
  }

  // ---- rare exact f64 fixup (wave 0, cooperative per flagged query) ----
  if ((tid >> 6) == 0){
    int lane = tid & 63;
    unsigned long long flags = __ballot(flag);
    int* pcnt = (int*)(smem + 8704);
    unsigned* pool = (unsigned*)(smem + 8708);
    while (flags){
      int L = __ffsll((long long)flags) - 1;
      flags &= flags - 1;
      int qf = tile*16 + L;
      float qx = __shfl(me.x, L), qy = __shfl(me.y, L), qz = __shfl(me.z, L);
      unsigned k16 = __shfl(key16, L);
      unsigned t16 = k16 >> 12;
      unsigned bhi = (t16 >= 0xFFFFDu) ? 0xFFFFFFFFu : ((t16 + 2) << 12);
      if (lane == 0) atomicExch(pcnt, 0);
      #pragma unroll 4
      for (int it = 0; it < 64; ++it){
        int m = it*64 + lane;
        float4 cd = pb[m];
        float dx = qx-cd.x, dy = qy-cd.y, dz = qz-cd.z;
        unsigned bits = __builtin_bit_cast(unsigned, dx*dx+dy*dy+dz*dz);
        if (m != qf && bits < bhi){
          int s = atomicAdd(pcnt, 1);
          if (s < 64) pool[s] = (unsigned)m;
        }
      }
      int pn = atomicAdd(pcnt, 0);
      if (pn > 64) pn = 64;
      unsigned long long kk = ~0ull;
      if (lane < pn){
        int m = pool[lane];
        float4 cd = pb[m];
        double ddx = (double)qx - (double)cd.x;
        double ddy = (double)qy - (double)cd.y;
        double ddz = (double)qz - (double)cd.z;
        double d2 = ddx*ddx + ddy*ddy + ddz*ddz;
        kk = (__builtin_bit_cast(unsigned long long, d2) & ~0xFFFull) | (unsigned)m;
      }
      #pragma unroll
      for (int k2 = 2; k2 <= 64; k2 <<= 1){
        #pragma unroll
        for (int j = k2 >> 1; j >= 1; j >>= 1){
          unsigned long long o = __shfl_xor(kk, j);
          bool up = ((lane & k2) == 0);
          bool keepmin = (((lane & j) == 0) == up);
          unsigned long long mn = kk < o ? kk : o;
          unsigned long long mx = kk < o ? o : kk;
          kk = keepmin ? mn : mx;
        }
      }
      if (lane < 16)
        IDXo[((size_t)(b*4096 + qf))*16 + lane] = (int)(unsigned)(kk & 0xFFFull);
    }
  }
}

// ---------------- ATTN: per-point fused kNN attention ----------------------
// 2 points/wave. LDS per wave: 4608B kv region [2 q][16 m][72 u16] (144B
// rows); t1 scratch (4KB) aliases it during setup. No softmax max-subtract.
__global__ __launch_bounds__(256) void k_attn(const float* __restrict__ pcoord,
    const int* __restrict__ IDX, const unsigned short* __restrict__ QKV,
    const unsigned short* __restrict__ W1F, const unsigned short* __restrict__ WD2F,
    const unsigned short* __restrict__ WDAF, const float* __restrict__ b_d2,
    const float* __restrict__ BALL, unsigned short* __restrict__ Y){
  __shared__ __align__(16) char smem[18432];
  __shared__ int idx_sh[4][2][16];
  int tid = threadIdx.x;
  int w = tid >> 6, lane = tid & 63;
  int m16 = lane & 15, g = lane >> 4;
  int P0 = blockIdx.x*8 + w*2;
  char* wbase = smem + w*4608;
  const f4 zf = {0.f, 0.f, 0.f, 0.f};
  if (lane < 16){
    #pragma unroll
    for (int q = 0; q < 2; ++q) idx_sh[w][q][lane] = IDX[(size_t)(P0 + q)*16 + lane];
  }
  // ---- setup: a[q][s] = A-frags of relu(rel_aug @ W1aug^T), t1 in alias ----
  unsigned short* t1s = (unsigned short*)wbase;
  s8 a[2][4];
  #pragma unroll
  for (int q = 0; q < 2; ++q){
    int pt = P0 + q;
    int bq = pt >> 12, nn = pt & 4095;
    const float* pb = pcoord + (size_t)bq*3*4096;
    s8 arel = {0,0,0,0,0,0,0,0};
    if (lane < 16){
      int jn = idx_sh[w][q][m16];
      float rx = pb[nn] - pb[jn];
      float ry = pb[4096 + nn] - pb[4096 + jn];
      float rz = pb[8192 + nn] - pb[8192 + jn];
      arel[0] = (short)f2bf(rx); arel[1] = (short)f2bf(ry);
      arel[2] = (short)f2bf(rz); arel[3] = (short)0x3F80;
    }
    f4 t1a[8];
    #pragma unroll
    for (int t = 0; t < 8; ++t){
      s8 bw = *(const s8*)(W1F + ((size_t)t*64 + lane)*8);
      t1a[t] = MFMA16(arel, bw, zf);
    }
    #pragma unroll
    for (int t = 0; t < 8; ++t){
      int c = t*16 + m16;
      #pragma unroll
      for (int r = 0; r < 4; ++r){
        int m = 4*g + r;
        int byt = (m*256 + c*2) ^ ((m & 7) << 4);
        t1s[byt >> 1] = f2bf(fmaxf(t1a[t][r], 0.f));
      }
    }
    const char* t1b = (const char*)t1s;
    #pragma unroll
    for (int s = 0; s < 4; ++s){
      int byt = (m16*256 + 64*s + 16*g) ^ ((m16 & 7) << 4);
      a[q][s] = *(const s8*)(t1b + byt);
    }
  }
  // ---- main: 4 passes over o-quarters ----
  #pragma unroll 1
  for (int pass = 0; pass < 4; ++pass){
    // WAR fence: previous pass's kv reads (or t1 reads) drain before overwrite
    asm volatile("s_waitcnt lgkmcnt(0)" ::: "memory");
    __builtin_amdgcn_sched_barrier(0);
    // gather this pass's kv columns + qa row
    uint4 gk[2][2];
    float qv[2];
    #pragma unroll
    for (int q = 0; q < 2; ++q){
      int pt = P0 + q, bq = pt >> 12;
      #pragma unroll
      for (int i2 = 0; i2 < 2; ++i2){
        int mm = i2*8 + (lane >> 3);
        int jn = idx_sh[w][q][mm];
        gk[q][i2] = *(const uint4*)((const char*)QKV
            + ((size_t)(bq*4096 + jn))*768 + pass*128 + (lane & 7)*16);
      }
      qv[q] = bf2f(QKV[(size_t)pt*384 + 256 + pass*32 + (lane & 31)]);
    }
    #pragma unroll
    for (int q = 0; q < 2; ++q){
      #pragma unroll
      for (int i2 = 0; i2 < 2; ++i2)
        *(uint4*)(wbase + q*2304 + (i2*8 + (lane >> 3))*144 + (lane & 7)*16) = gk[q][i2];
    }
    #pragma unroll
    for (int tl = 0; tl < 2; ++tl){
      int tg = pass*2 + tl;
      f4 dacc[2], lacc[2];
      #pragma unroll
      for (int q = 0; q < 2; ++q){ dacc[q] = zf; lacc[q] = zf; }
      #pragma unroll
      for (int s = 0; s < 4; ++s){
        s8 wd2 = *(const s8*)(WD2F + ((size_t)(tg*4 + s)*64 + lane)*8);
        s8 wda = *(const s8*)(WDAF + ((size_t)(tg*4 + s)*64 + lane)*8);
        #pragma unroll
        for (int q = 0; q < 2; ++q){
          dacc[q] = MFMA16(a[q][s], wd2, dacc[q]);
          lacc[q] = MFMA16(a[q][s], wda, lacc[q]);
        }
      }
      int col = tg*16 + m16;
      float bd2c = b_d2[col];
      float ballc = BALL[col];
      #pragma unroll
      for (int q = 0; q < 2; ++q){
        int pt = P0 + q;
        float qbase = __shfl(qv[q], tl*16 + m16) + ballc;
        float lg[4], dd[4], vv[4];
        #pragma unroll
        for (int r = 0; r < 4; ++r){
          int m = 4*g + r;
          unsigned kvp = *(const unsigned*)(wbase + q*2304 + m*144 + (tl*16 + m16)*4);
          float ka = bf2f((unsigned short)(kvp & 0xFFFFu));
          vv[r] = bf2f((unsigned short)(kvp >> 16));
          lg[r] = lacc[q][r] + qbase - ka;
          dd[r] = dacc[q][r] + bd2c;
        }
        // no max-subtraction: logits are O(10), overflow at 88
        float e0 = __expf(lg[0]), e1 = __expf(lg[1]);
        float e2 = __expf(lg[2]), e3 = __expf(lg[3]);
        float ss = e0 + e1 + e2 + e3;
        ss += __shfl_xor(ss, 16); ss += __shfl_xor(ss, 32);
        float inv = 1.f / ss;
        float yp = e0*(vv[0] + dd[0]) + e1*(vv[1] + dd[1])
                 + e2*(vv[2] + dd[2]) + e3*(vv[3] + dd[3]);
        yp *= inv;
        yp += __shfl_xor(yp, 16); yp += __shfl_xor(yp, 32);
        if (lane < 16) Y[(size_t)pt*128 + col] = f2bf(yp);
      }
    }
  }
}

// ---------------- D1: h2 = h + y ; d_out = h2 ; hn2 = LN2(h2) ---------------
__global__ __launch_bounds__(256) void k_d1(const float* __restrict__ H,
    const unsigned short* __restrict__ Y, const float* __restrict__ g2,
    const float* __restrict__ be2, float* __restrict__ outp,
    unsigned short* __restrict__ HN2){
  __shared__ float tile[128*65];
  int tid = threadIdx.x;
  int w = tid >> 6, lane = tid & 63;
  int pt16 = lane & 15, g = lane >> 4;
  int n64 = w*16 + pt16;
  int ptbase = blockIdx.x * 64;
  int pt = ptbase + n64;
  int c0 = g*32;
  const float4* h4 = (const float4*)(H + (size_t)pt*128 + c0);
  const uint4*  y4 = (const uint4*)((const char*)Y + (size_t)pt*256 + (size_t)c0*2);
  float h2[32];
  float ls = 0.f, lq = 0.f;
  #pragma unroll
  for (int i = 0; i < 4; ++i){
    float4 ha = h4[2*i], hb = h4[2*i + 1];
    uint4 yv = y4[i];
    float v0 = ha.x + bf2f((unsigned short)(yv.x & 0xFFFFu));
    float v1 = ha.y + bf2f((unsigned short)(yv.x >> 16));
    float v2 = ha.z + bf2f((unsigned short)(yv.y & 0xFFFFu));
    float v3 = ha.w + bf2f((unsigned short)(yv.y >> 16));
    float v4 = hb.x + bf2f((unsigned short)(yv.z & 0xFFFFu));
    float v5 = hb.y + bf2f((unsigned short)(yv.z >> 16));
    float v6 = hb.z + bf2f((unsigned short)(yv.w & 0xFFFFu));
    float v7 = hb.w + bf2f((unsigned short)(yv.w >> 16));
    h2[8*i+0]=v0; h2[8*i+1]=v1; h2[8*i+2]=v2; h2[8*i+3]=v3;
    h2[8*i+4]=v4; h2[8*i+5]=v5; h2[8*i+6]=v6; h2[8*i+7]=v7;
    ls += v0+v1+v2+v3+v4+v5+v6+v7;
    lq += v0*v0+v1*v1+v2*v2+v3*v3+v4*v4+v5*v5+v6*v6+v7*v7;
  }
  ls += __shfl_xor(ls, 16); ls += __shfl_xor(ls, 32);
  lq += __shfl_xor(lq, 16); lq += __shfl_xor(lq, 32);
  float mn = ls * (1.f/128.f);
  float vr = lq * (1.f/128.f) - mn*mn;
  float rs = rsqrtf(vr + 1e-5f);
  const float4* g4  = (const float4*)(g2 + c0);
  const float4* be4 = (const float4*)(be2 + c0);
  #pragma unroll
  for (int i = 0; i < 4; ++i){
    float4 ga = g4[2*i], gb = g4[2*i+1], ba = be4[2*i], bb2 = be4[2*i+1];
    unsigned uu[4];
    uu[0] = (unsigned)f2bf((h2[8*i+0]-mn)*rs*ga.x + ba.x)
          | ((unsigned)f2bf((h2[8*i+1]-mn)*rs*ga.y + ba.y) << 16);
    uu[1] = (unsigned)f2bf((h2[8*i+2]-mn)*rs*ga.z + ba.z)
          | ((unsigned)f2bf((h2[8*i+3]-mn)*rs*ga.w + ba.w) << 16);
    uu[2] = (unsigned)f2bf((h2[8*i+4]-mn)*rs*gb.x + bb2.x)
          | ((unsigned)f2bf((h2[8*i+5]-mn)*rs*gb.y + bb2.y) << 16);
    uu[3] = (unsigned)f2bf((h2[8*i+6]-mn)*rs*gb.z + bb2.z)
          | ((unsigned)f2bf((h2[8*i+7]-mn)*rs*gb.w + bb2.w) << 16);
    *(uint4*)((char*)HN2 + (size_t)pt*256 + (size_t)c0*2 + i*16)
        = make_uint4(uu[0], uu[1], uu[2], uu[3]);
  }
  int swz = g << 4;
  #pragma unroll
  for (int k = 0; k < 32; ++k)
    tile[(c0 + k)*65 + (n64 ^ swz)] = h2[k];
  __syncthreads();
  int bb = ptbase >> 12;
  int nb = ptbase & 4095;
  #pragma unroll 8
  for (int k = 0; k < 32; ++k){
    int c = w*32 + k;
    float v = tile[c*65 + (lane ^ ((((unsigned)c >> 5) & 3) << 4))];
    outp[(((size_t)(bb*128 + c)) << 12) | (unsigned)(nb + lane)] = v;
  }
}

// ---------------------------------------------------------------------------
extern "C" void kernel_launch(void* const* d_in, const int* in_sizes, int n_in,
                              void* d_out, int out_size, void* d_ws, size_t ws_size,
                              hipStream_t stream){
  const float* x    = (const float*)d_in[0];
  const float* p    = (const float*)d_in[1];
  const float* W_in = (const float*)d_in[2];
  const float* b_in = (const float*)d_in[3];
  const float* W_q  = (const float*)d_in[4];
  const float* W_k  = (const float*)d_in[5];
  const float* W_v  = (const float*)d_in[6];
  const float* W_d1 = (const float*)d_in[7];
  const float* b_d1 = (const float*)d_in[8];
  const float* W_d2 = (const float*)d_in[9];
  const float* b_d2 = (const float*)d_in[10];
  const float* W_a  = (const float*)d_in[11];
  const float* b_a  = (const float*)d_in[12];
  const float* g1   = (const float*)d_in[13];
  const float* be1  = (const float*)d_in[14];
  const float* g2   = (const float*)d_in[15];
  const float* be2  = (const float*)d_in[16];
  const float* W_f1 = (const float*)d_in[17];
  const float* b_f1 = (const float*)d_in[18];
  const float* W_f2 = (const float*)d_in[19];
  const float* b_f2 = (const float*)d_in[20];
  float* out = (float*)d_out;
  char* ws = (char*)d_ws;

  float*          H    = (float*)(ws + 0);
  unsigned short* HN   = (unsigned short*)(ws + 16777216);
  unsigned short* QKV  = (unsigned short*)(ws + 25165824);
  unsigned short* Z    = (unsigned short*)(ws + 16777216);  // alias HN+QKV
  unsigned short* Y    = (unsigned short*)(ws + 50331648);
  unsigned short* HN2  = (unsigned short*)(ws + 58720256);
  int*            IDX  = (int*)(ws + 67108864);
  float4*         PP   = (float4*)(ws + 69206016);
  char* tab = ws + 69730304;
  unsigned short* WCATF = (unsigned short*)(tab + 0);
  unsigned short* WF1F  = (unsigned short*)(tab + 98304);
  unsigned short* WF2F  = (unsigned short*)(tab + 229376);
  unsigned short* WD2F  = (unsigned short*)(tab + 360448);
  unsigned short* WDAF  = (unsigned short*)(tab + 393216);
  unsigned short* W1F   = (unsigned short*)(tab + 425984);
  unsigned short* WINF  = (unsigned short*)(tab + 434176);
  float*          BALL  = (float*)(tab + 450560);
  float*          TK    = (float*)(tab + 451072);
  float*          TQ    = (float*)(tab + 516608);
  float*          TD    = (float*)(tab + 582144);

  k_p1<<<dim3(384), dim3(128), 0, stream>>>(W_a, W_k, W_q, W_d2, TK, TQ, TD);
  k_pack<<<dim3(256), dim3(256), 0, stream>>>(p, W_v, W_d1, b_d1, W_in, W_f1, W_f2,
      W_a, b_a, b_d2, W_d2, TK, TQ, TD,
      PP, WCATF, WF1F, WF2F, WD2F, WDAF, W1F, WINF, BALL);
  k_knn<<<dim3(2048), dim3(128), 0, stream>>>(PP, IDX);
  k_a<<<dim3(512), dim3(256), 0, stream>>>(x, WINF, b_in, g1, be1, H, HN);
  k_gemm<0><<<dim3(512, 3), dim3(256), 0, stream>>>(HN, WCATF, nullptr, QKV);
  k_attn<<<dim3(4096), dim3(256), 0, stream>>>(p, IDX, QKV, W1F, WD2F, WDAF, b_d2, BALL, Y);
  k_d1<<<dim3(512), dim3(256), 0, stream>>>(H, Y, g2, be2, out, HN2);
  k_gemm<1><<<dim3(512, 4), dim3(256), 0, stream>>>(HN2, WF1F, b_f1, Z);
  k_f2<<<dim3(2, 256), dim3(256), 0, stream>>>(WF2F, Z, b_f2, out);
}